// Round 1
// baseline (3039.525 us; speedup 1.0000x reference)
//
#include <hip/hip_runtime.h>

#define N_NODES 100000
#define E_EDGES 1600000
#define IN_C 256
#define HID_C 128
#define OUT_C 64
#define BN_EPS 1e-5f

// ---------- edge index accessors (int32 vs int64 detected at runtime) ----------
__device__ __forceinline__ int edge_src(const int* ei, int e, int is64) {
    return is64 ? ei[2 * e] : ei[e];
}
__device__ __forceinline__ int edge_dst(const int* ei, int e, int is64) {
    return is64 ? ei[2 * E_EDGES + 2 * e] : ei[E_EDGES + e];
}

// flag=1 if int64 (all odd int32 words of the first chunk are zero high-words)
__global__ void detect_dtype(const int* __restrict__ ei, int* __restrict__ flag) {
    __shared__ int any;
    if (threadIdx.x == 0) any = 0;
    __syncthreads();
    int v = 0;
    for (int i = threadIdx.x; i < 4096; i += blockDim.x) v |= ei[2 * i + 1];
    if (v) atomicOr(&any, 1);
    __syncthreads();
    if (threadIdx.x == 0) *flag = any ? 0 : 1;
}

// ---------- degree / normalization ----------
__global__ void deg_count(const int* __restrict__ ei, const int* __restrict__ flag,
                          float* __restrict__ deg) {
    int is64 = *flag;
    int i = blockIdx.x * blockDim.x + threadIdx.x;
    int stride = gridDim.x * blockDim.x;
    for (int e = i; e < E_EDGES; e += stride)
        atomicAdd(&deg[edge_dst(ei, e, is64)], 1.0f);
}

__global__ void finish_dis(float* __restrict__ dis) {
    int i = blockIdx.x * blockDim.x + threadIdx.x;
    if (i < N_NODES) dis[i] = rsqrtf(1.0f + dis[i]);
}

// ---------- fp32 tiled GEMM: C[M,128] = A[M,K] @ W[K,128] ----------
template <int K>
__global__ __launch_bounds__(256) void gemm_tile(const float* __restrict__ A,
                                                 const float* __restrict__ W,
                                                 float* __restrict__ C, int M) {
    __shared__ float xs[64][17];   // +1 pad: avoid bank conflicts on column reads
    __shared__ float ws[16][128];
    int row0 = blockIdx.x * 64;
    int tx = threadIdx.x & 31;   // cols tx*4 .. tx*4+3
    int ty = threadIdx.x >> 5;   // rows ty*8 .. ty*8+7
    float acc[8][4] = {};
    for (int k0 = 0; k0 < K; k0 += 16) {
        for (int t = threadIdx.x; t < 64 * 16; t += 256) {
            int r = t >> 4, kk = t & 15;
            int row = row0 + r;
            xs[r][kk] = (row < M) ? A[(size_t)row * K + k0 + kk] : 0.f;
        }
        for (int t = threadIdx.x; t < 16 * 128; t += 256) {
            int kr = t >> 7, c = t & 127;
            ws[kr][c] = W[(size_t)(k0 + kr) * 128 + c];
        }
        __syncthreads();
        #pragma unroll
        for (int kk = 0; kk < 16; ++kk) {
            float b0 = ws[kk][tx * 4 + 0], b1 = ws[kk][tx * 4 + 1];
            float b2 = ws[kk][tx * 4 + 2], b3 = ws[kk][tx * 4 + 3];
            #pragma unroll
            for (int i = 0; i < 8; ++i) {
                float a = xs[ty * 8 + i][kk];
                acc[i][0] += a * b0; acc[i][1] += a * b1;
                acc[i][2] += a * b2; acc[i][3] += a * b3;
            }
        }
        __syncthreads();
    }
    for (int i = 0; i < 8; ++i) {
        int row = row0 + ty * 8 + i;
        if (row < M) {
            float4 v = {acc[i][0], acc[i][1], acc[i][2], acc[i][3]};
            *(float4*)&C[(size_t)row * 128 + tx * 4] = v;
        }
    }
}

// ---------- elementwise: hpre = h*self_w + b1 ----------
__global__ void init_hpre(const float* __restrict__ h, const float* __restrict__ dis,
                          const float* __restrict__ b1, float* __restrict__ hpre) {
    size_t t = (size_t)blockIdx.x * blockDim.x + threadIdx.x;  // float4 units
    if (t >= (size_t)N_NODES * 32) return;
    int n = (int)(t >> 5), q = (int)(t & 31);
    float d = dis[n]; float sw = d * d;
    float4 hv = ((const float4*)h)[t];
    float4 bv = ((const float4*)b1)[q];
    float4 o = {hv.x * sw + bv.x, hv.y * sw + bv.y, hv.z * sw + bv.z, hv.w * sw + bv.w};
    ((float4*)hpre)[t] = o;
}

// ---------- edge scatter: one 64-lane wave per edge, float2 per lane ----------
__global__ void scatter_add(const float* __restrict__ h, const int* __restrict__ ei,
                            const int* __restrict__ flag, const float* __restrict__ dis,
                            float* __restrict__ out) {
    int is64 = *flag;
    int gtid = blockIdx.x * blockDim.x + threadIdx.x;
    int lane = gtid & 63;
    int wave = gtid >> 6;
    int nwaves = (gridDim.x * blockDim.x) >> 6;
    for (int e = wave; e < E_EDGES; e += nwaves) {
        int s = edge_src(ei, e, is64);
        int d = edge_dst(ei, e, is64);
        float w = dis[s] * dis[d];
        float2 v = ((const float2*)(h + (size_t)s * 128))[lane];
        float* op = out + (size_t)d * 128 + lane * 2;
        atomicAdd(op, v.x * w);
        atomicAdd(op + 1, v.y * w);
    }
}

// scatter directly into d_out (c<64 -> xm, else x_)
__global__ void scatter_add_out(const float* __restrict__ h, const int* __restrict__ ei,
                                const int* __restrict__ flag, const float* __restrict__ dis,
                                float* __restrict__ out) {
    int is64 = *flag;
    int gtid = blockIdx.x * blockDim.x + threadIdx.x;
    int lane = gtid & 63;
    int wave = gtid >> 6;
    int nwaves = (gridDim.x * blockDim.x) >> 6;
    for (int e = wave; e < E_EDGES; e += nwaves) {
        int s = edge_src(ei, e, is64);
        int d = edge_dst(ei, e, is64);
        float w = dis[s] * dis[d];
        float2 v = ((const float2*)(h + (size_t)s * 128))[lane];
        int c = lane * 2;
        size_t off = (c < 64) ? ((size_t)d * 64 + c)
                              : ((size_t)N_NODES * 64 + (size_t)d * 64 + (c - 64));
        atomicAdd(out + off, v.x * w);
        atomicAdd(out + off + 1, v.y * w);
    }
}

// ---------- batch norm ----------
__global__ void bn_stats(const float* __restrict__ hpre, float* __restrict__ stats) {
    int c = threadIdx.x & 127;
    int half = threadIdx.x >> 7;
    float s = 0.f, s2 = 0.f;
    int rpi = (blockDim.x >> 7) * gridDim.x;
    for (int n = blockIdx.x * 2 + half; n < N_NODES; n += rpi) {
        float v = hpre[(size_t)n * 128 + c];
        s += v; s2 += v * v;
    }
    __shared__ float ls[256], ls2[256];
    ls[threadIdx.x] = s; ls2[threadIdx.x] = s2;
    __syncthreads();
    if (threadIdx.x < 128) {
        s = ls[threadIdx.x] + ls[threadIdx.x + 128];
        s2 = ls2[threadIdx.x] + ls2[threadIdx.x + 128];
        atomicAdd(&stats[c], s);
        atomicAdd(&stats[128 + c], s2);
    }
}

__global__ void bn_finish(float* __restrict__ stats, const float* __restrict__ gamma,
                          const float* __restrict__ beta) {
    int c = threadIdx.x;
    if (c < 128) {
        float mean = stats[c] * (1.0f / N_NODES);
        float var = stats[128 + c] * (1.0f / N_NODES) - mean * mean;
        float scale = rsqrtf(var + BN_EPS) * gamma[c];
        stats[256 + c] = scale;
        stats[384 + c] = beta[c] - mean * scale;
    }
}

__global__ void bn_relu(const float* __restrict__ hpre, const float* __restrict__ stats,
                        float* __restrict__ h1) {
    size_t t = (size_t)blockIdx.x * blockDim.x + threadIdx.x;  // float4 units
    if (t >= (size_t)N_NODES * 32) return;
    int q = (int)(t & 31);
    float4 v = ((const float4*)hpre)[t];
    float4 sc = ((const float4*)(stats + 256))[q];
    float4 sh = ((const float4*)(stats + 384))[q];
    float4 o;
    o.x = fmaxf(v.x * sc.x + sh.x, 0.f);
    o.y = fmaxf(v.y * sc.y + sh.y, 0.f);
    o.z = fmaxf(v.z * sc.z + sh.z, 0.f);
    o.w = fmaxf(v.w * sc.w + sh.w, 0.f);
    ((float4*)h1)[t] = o;
}

// ---------- concat W2|W3 into one [128,128] ----------
__global__ void build_wcat(const float* __restrict__ W2, const float* __restrict__ W3,
                           float* __restrict__ Wcat) {
    int t = blockIdx.x * blockDim.x + threadIdx.x;
    if (t >= 128 * 128) return;
    int k = t >> 7, c = t & 127;
    Wcat[t] = (c < 64) ? W2[k * 64 + c] : W3[k * 64 + (c - 64)];
}

// ---------- init output with self-term + bias ----------
__global__ void init_out(const float* __restrict__ t2, const float* __restrict__ dis,
                         const float* __restrict__ b2, const float* __restrict__ b3,
                         float* __restrict__ out) {
    size_t t = (size_t)blockIdx.x * blockDim.x + threadIdx.x;
    if (t >= (size_t)N_NODES * 128) return;
    int n = (int)(t >> 7), c = (int)(t & 127);
    float d = dis[n]; float sw = d * d;
    float v = t2[t] * sw + ((c < 64) ? b2[c] : b3[c - 64]);
    size_t off = (c < 64) ? ((size_t)n * 64 + c)
                          : ((size_t)N_NODES * 64 + (size_t)n * 64 + (c - 64));
    out[off] = v;
}

extern "C" void kernel_launch(void* const* d_in, const int* in_sizes, int n_in,
                              void* d_out, int out_size, void* d_ws, size_t ws_size,
                              hipStream_t stream) {
    const float* x    = (const float*)d_in[0];
    const int* ei     = (const int*)d_in[1];
    const float* W1   = (const float*)d_in[2];
    const float* b1   = (const float*)d_in[3];
    const float* gamma= (const float*)d_in[4];
    const float* beta = (const float*)d_in[5];
    const float* W2   = (const float*)d_in[6];
    const float* b2   = (const float*)d_in[7];
    const float* W3   = (const float*)d_in[8];
    const float* b3   = (const float*)d_in[9];
    float* out = (float*)d_out;

    char* ws = (char*)d_ws;
    const size_t BUF = (size_t)N_NODES * 128 * 4;  // 51.2 MB
    float* dis   = (float*)ws;                          // N floats
    float* A     = (float*)(ws + 524288);               // h / h1
    float* B     = (float*)(ws + 524288 + BUF);         // hpre / t
    float* Wcat  = (float*)(ws + 524288 + 2 * BUF);
    float* stats = (float*)(ws + 524288 + 2 * BUF + 65536);
    int*   flag  = (int*)  (ws + 524288 + 2 * BUF + 65536 + 4096);

    hipMemsetAsync(dis, 0, N_NODES * 4, stream);
    hipMemsetAsync(stats, 0, 1024, stream);
    detect_dtype<<<1, 256, 0, stream>>>(ei, flag);
    deg_count<<<1024, 256, 0, stream>>>(ei, flag, dis);
    finish_dis<<<(N_NODES + 255) / 256, 256, 0, stream>>>(dis);

    // layer 1
    gemm_tile<IN_C><<<(N_NODES + 63) / 64, 256, 0, stream>>>(x, W1, A, N_NODES);
    init_hpre<<<(N_NODES * 32 + 255) / 256, 256, 0, stream>>>(A, dis, b1, B);
    scatter_add<<<2048, 256, 0, stream>>>(A, ei, flag, dis, B);
    bn_stats<<<512, 256, 0, stream>>>(B, stats);
    bn_finish<<<1, 128, 0, stream>>>(stats, gamma, beta);
    bn_relu<<<(N_NODES * 32 + 255) / 256, 256, 0, stream>>>(B, stats, A);

    // layer 2 (both heads fused)
    build_wcat<<<64, 256, 0, stream>>>(W2, W3, Wcat);
    gemm_tile<HID_C><<<(N_NODES + 63) / 64, 256, 0, stream>>>(A, Wcat, B, N_NODES);
    init_out<<<(N_NODES * 128 + 255) / 256, 256, 0, stream>>>(B, dis, b2, b3, out);
    scatter_add_out<<<2048, 256, 0, stream>>>(B, ei, flag, dis, out);
}

// Round 2
// 760.851 us; speedup vs baseline: 3.9949x; 3.9949x over previous
//
#include <hip/hip_runtime.h>

#define N_NODES 100000
#define E_EDGES 1600000
#define IN_C 256
#define HID_C 128
#define BN_EPS 1e-5f

// ---------- edge index accessors (int32 vs int64 detected at runtime) ----------
__device__ __forceinline__ int edge_src(const int* ei, int e, int is64) {
    return is64 ? ei[2 * e] : ei[e];
}
__device__ __forceinline__ int edge_dst(const int* ei, int e, int is64) {
    return is64 ? ei[2 * E_EDGES + 2 * e] : ei[E_EDGES + e];
}

// flag=1 if int64 (all odd int32 words of the first chunk are zero high-words)
__global__ void detect_dtype(const int* __restrict__ ei, int* __restrict__ flag) {
    __shared__ int any;
    if (threadIdx.x == 0) any = 0;
    __syncthreads();
    int v = 0;
    for (int i = threadIdx.x; i < 4096; i += blockDim.x) v |= ei[2 * i + 1];
    if (v) atomicOr(&any, 1);
    __syncthreads();
    if (threadIdx.x == 0) *flag = any ? 0 : 1;
}

// ---------- degree histogram (int) ----------
__global__ void deg_count(const int* __restrict__ ei, const int* __restrict__ flag,
                          int* __restrict__ degi) {
    int is64 = *flag;
    int i = blockIdx.x * blockDim.x + threadIdx.x;
    int stride = gridDim.x * blockDim.x;
    for (int e = i; e < E_EDGES; e += stride)
        atomicAdd(&degi[edge_dst(ei, e, is64)], 1);
}

__global__ void finish_dis(const int* __restrict__ degi, float* __restrict__ dis) {
    int i = blockIdx.x * blockDim.x + threadIdx.x;
    if (i < N_NODES) dis[i] = rsqrtf(1.0f + (float)degi[i]);
}

// ---------- 3-phase exclusive prefix scan over degi -> rowptr ----------
__global__ void scan_phase1(const int* __restrict__ degi, int* __restrict__ rowptr,
                            int* __restrict__ part) {
    __shared__ int sh[256];
    int i = blockIdx.x * 256 + threadIdx.x;
    int v = (i < N_NODES) ? degi[i] : 0;
    sh[threadIdx.x] = v;
    __syncthreads();
    for (int off = 1; off < 256; off <<= 1) {
        int t = (threadIdx.x >= off) ? sh[threadIdx.x - off] : 0;
        __syncthreads();
        sh[threadIdx.x] += t;
        __syncthreads();
    }
    if (i < N_NODES) rowptr[i] = sh[threadIdx.x] - v;  // exclusive
    if (threadIdx.x == 255) part[blockIdx.x] = sh[255];
}

__global__ void scan_phase2(int* __restrict__ part, int nb) {
    __shared__ int sh[512];
    int tid = threadIdx.x;
    int v = (tid < nb) ? part[tid] : 0;
    sh[tid] = v;
    __syncthreads();
    for (int off = 1; off < 512; off <<= 1) {
        int t = (tid >= off) ? sh[tid - off] : 0;
        __syncthreads();
        sh[tid] += t;
        __syncthreads();
    }
    if (tid < nb) part[tid] = sh[tid] - v;  // exclusive
}

__global__ void scan_phase3(int* __restrict__ rowptr, const int* __restrict__ part,
                            int* __restrict__ cursor) {
    int i = blockIdx.x * 256 + threadIdx.x;
    if (i < N_NODES) {
        int r = rowptr[i] + part[blockIdx.x];
        rowptr[i] = r;
        cursor[i] = r;
    }
    if (i == N_NODES - 1) rowptr[N_NODES] = E_EDGES;
}

// ---------- CSR fill: bucket src ids by dst ----------
__global__ void csr_fill(const int* __restrict__ ei, const int* __restrict__ flag,
                         int* __restrict__ cursor, int* __restrict__ csr_src) {
    int is64 = *flag;
    int i = blockIdx.x * blockDim.x + threadIdx.x;
    int stride = gridDim.x * blockDim.x;
    for (int e = i; e < E_EDGES; e += stride) {
        int s = edge_src(ei, e, is64);
        int d = edge_dst(ei, e, is64);
        int pos = atomicAdd(&cursor[d], 1);
        csr_src[pos] = s;
    }
}

// ---------- fp32 tiled GEMM: C[M,128] = A[M,K] @ W[K,128] ----------
template <int K>
__global__ __launch_bounds__(256) void gemm_tile(const float* __restrict__ A,
                                                 const float* __restrict__ W,
                                                 float* __restrict__ C, int M) {
    __shared__ float xs[64][17];
    __shared__ float ws[16][128];
    int row0 = blockIdx.x * 64;
    int tx = threadIdx.x & 31;
    int ty = threadIdx.x >> 5;
    float acc[8][4] = {};
    for (int k0 = 0; k0 < K; k0 += 16) {
        for (int t = threadIdx.x; t < 64 * 16; t += 256) {
            int r = t >> 4, kk = t & 15;
            int row = row0 + r;
            xs[r][kk] = (row < M) ? A[(size_t)row * K + k0 + kk] : 0.f;
        }
        for (int t = threadIdx.x; t < 16 * 128; t += 256) {
            int kr = t >> 7, c = t & 127;
            ws[kr][c] = W[(size_t)(k0 + kr) * 128 + c];
        }
        __syncthreads();
        #pragma unroll
        for (int kk = 0; kk < 16; ++kk) {
            float b0 = ws[kk][tx * 4 + 0], b1 = ws[kk][tx * 4 + 1];
            float b2 = ws[kk][tx * 4 + 2], b3 = ws[kk][tx * 4 + 3];
            #pragma unroll
            for (int i = 0; i < 8; ++i) {
                float a = xs[ty * 8 + i][kk];
                acc[i][0] += a * b0; acc[i][1] += a * b1;
                acc[i][2] += a * b2; acc[i][3] += a * b3;
            }
        }
        __syncthreads();
    }
    for (int i = 0; i < 8; ++i) {
        int row = row0 + ty * 8 + i;
        if (row < M) {
            float4 v = {acc[i][0], acc[i][1], acc[i][2], acc[i][3]};
            *(float4*)&C[(size_t)row * 128 + tx * 4] = v;
        }
    }
}

// ---------- CSR aggregation: one wave per dst node; fused self-term + bias ----------
// SPLIT=0: out[n*128 + c]  SPLIT=1: c<64 -> out[n*64+c], else out[N*64 + n*64 + c-64]
template <int SPLIT>
__global__ __launch_bounds__(256) void aggregate(const float* __restrict__ h,
                                                 const int* __restrict__ csr_src,
                                                 const int* __restrict__ rowptr,
                                                 const float* __restrict__ dis,
                                                 const float* __restrict__ bias,
                                                 float* __restrict__ out) {
    int wid = (blockIdx.x * 256 + threadIdx.x) >> 6;
    int lane = threadIdx.x & 63;
    if (wid >= N_NODES) return;
    int beg = rowptr[wid], end = rowptr[wid + 1];
    float dn = dis[wid];
    float2 self = ((const float2*)(h + (size_t)wid * 128))[lane];
    float2 bv = ((const float2*)bias)[lane];
    float sw = dn * dn;
    float2 acc;
    acc.x = self.x * sw + bv.x;
    acc.y = self.y * sw + bv.y;
    for (int c = beg; c < end; c += 64) {
        int idx = c + lane;
        int sl = (idx < end) ? csr_src[idx] : 0;
        float wl = (idx < end) ? dis[sl] * dn : 0.0f;
        int cnt = min(64, end - c);
        for (int j = 0; j < cnt; ++j) {
            int s = __shfl(sl, j);
            float w = __shfl(wl, j);
            float2 v = ((const float2*)(h + (size_t)s * 128))[lane];
            acc.x += v.x * w;
            acc.y += v.y * w;
        }
    }
    if (SPLIT == 0) {
        ((float2*)(out + (size_t)wid * 128))[lane] = acc;
    } else {
        int ch = lane * 2;
        size_t off = (ch < 64) ? ((size_t)wid * 64 + ch)
                               : ((size_t)(N_NODES + wid) * 64 + (ch - 64));
        *(float2*)(out + off) = acc;
    }
}

// ---------- batch norm ----------
__global__ void bn_stats(const float* __restrict__ hpre, float* __restrict__ stats) {
    int c = threadIdx.x & 127;
    int half = threadIdx.x >> 7;
    float s = 0.f, s2 = 0.f;
    int rpi = (blockDim.x >> 7) * gridDim.x;
    for (int n = blockIdx.x * 2 + half; n < N_NODES; n += rpi) {
        float v = hpre[(size_t)n * 128 + c];
        s += v; s2 += v * v;
    }
    __shared__ float ls[256], ls2[256];
    ls[threadIdx.x] = s; ls2[threadIdx.x] = s2;
    __syncthreads();
    if (threadIdx.x < 128) {
        s = ls[threadIdx.x] + ls[threadIdx.x + 128];
        s2 = ls2[threadIdx.x] + ls2[threadIdx.x + 128];
        atomicAdd(&stats[c], s);
        atomicAdd(&stats[128 + c], s2);
    }
}

__global__ void bn_finish(float* __restrict__ stats, const float* __restrict__ gamma,
                          const float* __restrict__ beta) {
    int c = threadIdx.x;
    if (c < 128) {
        float mean = stats[c] * (1.0f / N_NODES);
        float var = stats[128 + c] * (1.0f / N_NODES) - mean * mean;
        float scale = rsqrtf(var + BN_EPS) * gamma[c];
        stats[256 + c] = scale;
        stats[384 + c] = beta[c] - mean * scale;
    }
}

__global__ void bn_relu(float* __restrict__ hpre, const float* __restrict__ stats) {
    size_t t = (size_t)blockIdx.x * blockDim.x + threadIdx.x;  // float4 units
    if (t >= (size_t)N_NODES * 32) return;
    int q = (int)(t & 31);
    float4 v = ((float4*)hpre)[t];
    float4 sc = ((const float4*)(stats + 256))[q];
    float4 sh = ((const float4*)(stats + 384))[q];
    float4 o;
    o.x = fmaxf(v.x * sc.x + sh.x, 0.f);
    o.y = fmaxf(v.y * sc.y + sh.y, 0.f);
    o.z = fmaxf(v.z * sc.z + sh.z, 0.f);
    o.w = fmaxf(v.w * sc.w + sh.w, 0.f);
    ((float4*)hpre)[t] = o;
}

// ---------- concat W2|W3 -> Wcat[128,128], b2|b3 -> bcat[128] ----------
__global__ void build_wcat(const float* __restrict__ W2, const float* __restrict__ W3,
                           const float* __restrict__ b2, const float* __restrict__ b3,
                           float* __restrict__ Wcat, float* __restrict__ bcat) {
    int t = blockIdx.x * blockDim.x + threadIdx.x;
    if (t < 128 * 128) {
        int k = t >> 7, c = t & 127;
        Wcat[t] = (c < 64) ? W2[k * 64 + c] : W3[k * 64 + (c - 64)];
    }
    if (t < 128) bcat[t] = (t < 64) ? b2[t] : b3[t - 64];
}

extern "C" void kernel_launch(void* const* d_in, const int* in_sizes, int n_in,
                              void* d_out, int out_size, void* d_ws, size_t ws_size,
                              hipStream_t stream) {
    const float* x    = (const float*)d_in[0];
    const int* ei     = (const int*)d_in[1];
    const float* W1   = (const float*)d_in[2];
    const float* b1   = (const float*)d_in[3];
    const float* gamma= (const float*)d_in[4];
    const float* beta = (const float*)d_in[5];
    const float* W2   = (const float*)d_in[6];
    const float* b2   = (const float*)d_in[7];
    const float* W3   = (const float*)d_in[8];
    const float* b3   = (const float*)d_in[9];
    float* out = (float*)d_out;

    char* p = (char*)d_ws;
    auto alloc = [&](size_t bytes) {
        void* r = (void*)p;
        p += (bytes + 511) & ~(size_t)511;
        return r;
    };
    float* dis    = (float*)alloc(N_NODES * 4);
    int*   degi   = (int*)  alloc(N_NODES * 4);          // reused as cursor
    int*   rowptr = (int*)  alloc((N_NODES + 1) * 4);
    int*   part   = (int*)  alloc(2048);
    float* stats  = (float*)alloc(2048);
    int*   flag   = (int*)  alloc(256);
    float* Wcat   = (float*)alloc(128 * 128 * 4);
    float* bcat   = (float*)alloc(512);
    int*   csrs   = (int*)  alloc((size_t)E_EDGES * 4);
    float* A      = (float*)alloc((size_t)N_NODES * 128 * 4);
    float* B      = (float*)alloc((size_t)N_NODES * 128 * 4);

    const int NB = (N_NODES + 255) / 256;  // 391

    hipMemsetAsync(degi, 0, N_NODES * 4, stream);
    hipMemsetAsync(stats, 0, 1024, stream);

    detect_dtype<<<1, 256, 0, stream>>>(ei, flag);
    deg_count<<<1024, 256, 0, stream>>>(ei, flag, degi);
    finish_dis<<<NB, 256, 0, stream>>>(degi, dis);

    // CSR build
    scan_phase1<<<NB, 256, 0, stream>>>(degi, rowptr, part);
    scan_phase2<<<1, 512, 0, stream>>>(part, NB);
    scan_phase3<<<NB, 256, 0, stream>>>(rowptr, part, degi /*cursor*/);
    csr_fill<<<1024, 256, 0, stream>>>(ei, flag, degi /*cursor*/, csrs);

    // layer 1: h = x@W1 ; hpre = agg(h) + h*sw + b1 ; BN ; ReLU
    gemm_tile<IN_C><<<(N_NODES + 63) / 64, 256, 0, stream>>>(x, W1, A, N_NODES);
    aggregate<0><<<(N_NODES * 64 + 255) / 256, 256, 0, stream>>>(A, csrs, rowptr, dis, b1, B);
    bn_stats<<<512, 256, 0, stream>>>(B, stats);
    bn_finish<<<1, 128, 0, stream>>>(stats, gamma, beta);
    bn_relu<<<(N_NODES * 32 + 255) / 256, 256, 0, stream>>>(B, stats);

    // layer 2 (both heads fused): t = h1@[W2|W3] ; out = agg(t) + t*sw + bcat
    build_wcat<<<64, 256, 0, stream>>>(W2, W3, b2, b3, Wcat, bcat);
    gemm_tile<HID_C><<<(N_NODES + 63) / 64, 256, 0, stream>>>(B, Wcat, A, N_NODES);
    aggregate<1><<<(N_NODES * 64 + 255) / 256, 256, 0, stream>>>(A, csrs, rowptr, dis, bcat, out);
}

// Round 3
// 572.375 us; speedup vs baseline: 5.3104x; 1.3293x over previous
//
#include <hip/hip_runtime.h>

#define N_NODES 100000
#define E_EDGES 1600000
#define IN_C 256
#define HID_C 128
#define BN_EPS 1e-5f

using v8s = __attribute__((ext_vector_type(8))) short;
using v4f = __attribute__((ext_vector_type(4))) float;
using v8u = __attribute__((ext_vector_type(8))) unsigned short;

// float -> bf16, round-to-nearest-even
__device__ __forceinline__ unsigned short f2bf(float f) {
    unsigned int u = __float_as_uint(f);
    u += 0x7fffu + ((u >> 16) & 1u);
    return (unsigned short)(u >> 16);
}

// ---------- edge index accessors (int32 vs int64 detected at runtime) ----------
__device__ __forceinline__ int edge_src(const int* ei, int e, int is64) {
    return is64 ? ei[2 * e] : ei[e];
}
__device__ __forceinline__ int edge_dst(const int* ei, int e, int is64) {
    return is64 ? ei[2 * E_EDGES + 2 * e] : ei[E_EDGES + e];
}

__global__ void detect_dtype(const int* __restrict__ ei, int* __restrict__ flag) {
    __shared__ int any;
    if (threadIdx.x == 0) any = 0;
    __syncthreads();
    int v = 0;
    for (int i = threadIdx.x; i < 4096; i += blockDim.x) v |= ei[2 * i + 1];
    if (v) atomicOr(&any, 1);
    __syncthreads();
    if (threadIdx.x == 0) *flag = any ? 0 : 1;
}

// ---------- degree histogram ----------
__global__ void deg_count(const int* __restrict__ ei, const int* __restrict__ flag,
                          int* __restrict__ degi) {
    int is64 = *flag;
    int i = blockIdx.x * blockDim.x + threadIdx.x;
    int stride = gridDim.x * blockDim.x;
    for (int e = i; e < E_EDGES; e += stride)
        atomicAdd(&degi[edge_dst(ei, e, is64)], 1);
}

__global__ void finish_dis(const int* __restrict__ degi, float* __restrict__ dis) {
    int i = blockIdx.x * blockDim.x + threadIdx.x;
    if (i < N_NODES) dis[i] = rsqrtf(1.0f + (float)degi[i]);
}

// ---------- 3-phase exclusive scan -> rowptr ----------
__global__ void scan_phase1(const int* __restrict__ degi, int* __restrict__ rowptr,
                            int* __restrict__ part) {
    __shared__ int sh[256];
    int i = blockIdx.x * 256 + threadIdx.x;
    int v = (i < N_NODES) ? degi[i] : 0;
    sh[threadIdx.x] = v;
    __syncthreads();
    for (int off = 1; off < 256; off <<= 1) {
        int t = (threadIdx.x >= off) ? sh[threadIdx.x - off] : 0;
        __syncthreads();
        sh[threadIdx.x] += t;
        __syncthreads();
    }
    if (i < N_NODES) rowptr[i] = sh[threadIdx.x] - v;
    if (threadIdx.x == 255) part[blockIdx.x] = sh[255];
}

__global__ void scan_phase2(int* __restrict__ part, int nb) {
    __shared__ int sh[512];
    int tid = threadIdx.x;
    int v = (tid < nb) ? part[tid] : 0;
    sh[tid] = v;
    __syncthreads();
    for (int off = 1; off < 512; off <<= 1) {
        int t = (tid >= off) ? sh[tid - off] : 0;
        __syncthreads();
        sh[tid] += t;
        __syncthreads();
    }
    if (tid < nb) part[tid] = sh[tid] - v;
}

__global__ void scan_phase3(int* __restrict__ rowptr, const int* __restrict__ part,
                            int* __restrict__ cursor) {
    int i = blockIdx.x * 256 + threadIdx.x;
    if (i < N_NODES) {
        int r = rowptr[i] + part[blockIdx.x];
        rowptr[i] = r;
        cursor[i] = r;
    }
    if (i == N_NODES - 1) rowptr[N_NODES] = E_EDGES;
}

__global__ void csr_fill(const int* __restrict__ ei, const int* __restrict__ flag,
                         int* __restrict__ cursor, int* __restrict__ csr_src) {
    int is64 = *flag;
    int i = blockIdx.x * blockDim.x + threadIdx.x;
    int stride = gridDim.x * blockDim.x;
    for (int e = i; e < E_EDGES; e += stride) {
        int s = edge_src(ei, e, is64);
        int d = edge_dst(ei, e, is64);
        int pos = atomicAdd(&cursor[d], 1);
        csr_src[pos] = s;
    }
}

// ---------- W permute into B-frag order (bf16) ----------
// b-frag elem j of lane l, col-tile ct, k-tile kt:
//   k = kt*32 + (l>>4)*4 + (j&3) + 16*(j>>2),  n = ct*16 + (l&15)
__global__ void wperm(const float* __restrict__ W, unsigned short* __restrict__ Wp, int K) {
    int t = blockIdx.x * 256 + threadIdx.x;
    if (t >= K * 128) return;
    int j = t & 7, l = (t >> 3) & 63, ct = (t >> 9) & 7, kt = t >> 12;
    int k = kt * 32 + ((l >> 4) << 2) + (j & 3) + ((j >> 2) << 4);
    int n = ct * 16 + (l & 15);
    Wp[t] = f2bf(W[k * 128 + n]);
}

// ---------- MFMA GEMM: C[M,128] = A[M,K] @ W[K,128] ----------
// 4 waves/block, wave handles 16 rows x 128 cols. W pre-permuted bf16 in global.
template <int K, bool BF16IN>
__global__ __launch_bounds__(256) void gemm_mfma(const void* __restrict__ Ain,
                                                 const unsigned short* __restrict__ Wp,
                                                 float* __restrict__ C, int M) {
    int wave = threadIdx.x >> 6;
    int l = threadIdx.x & 63;
    int kg = l >> 4;                     // 0..3
    int row = blockIdx.x * 64 + wave * 16 + (l & 15);
    int rl = min(row, M - 1);

    v4f acc[8];
    #pragma unroll
    for (int i = 0; i < 8; ++i)
        for (int r = 0; r < 4; ++r) acc[i][r] = 0.f;

    #pragma unroll
    for (int kt = 0; kt < K / 32; ++kt) {
        v8s a;
        if constexpr (!BF16IN) {
            const float* A = (const float*)Ain;
            float4 u = *(const float4*)(A + (size_t)rl * K + kt * 32 + kg * 4);
            float4 v = *(const float4*)(A + (size_t)rl * K + kt * 32 + 16 + kg * 4);
            a[0] = f2bf(u.x); a[1] = f2bf(u.y); a[2] = f2bf(u.z); a[3] = f2bf(u.w);
            a[4] = f2bf(v.x); a[5] = f2bf(v.y); a[6] = f2bf(v.z); a[7] = f2bf(v.w);
        } else {
            const unsigned short* A = (const unsigned short*)Ain;
            union { struct { uint2 lo, hi; } q; v8s s; } u8;
            u8.q.lo = *(const uint2*)(A + (size_t)rl * K + kt * 32 + kg * 4);
            u8.q.hi = *(const uint2*)(A + (size_t)rl * K + kt * 32 + 16 + kg * 4);
            a = u8.s;
        }
        const v8s* bp = (const v8s*)Wp + (size_t)(kt * 8) * 64 + l;
        #pragma unroll
        for (int ct = 0; ct < 8; ++ct) {
            v8s b = bp[ct * 64];
            acc[ct] = __builtin_amdgcn_mfma_f32_16x16x32_bf16(a, b, acc[ct], 0, 0, 0);
        }
    }

    int orow0 = blockIdx.x * 64 + wave * 16 + kg * 4;
    #pragma unroll
    for (int ct = 0; ct < 8; ++ct) {
        #pragma unroll
        for (int r = 0; r < 4; ++r) {
            int orow = orow0 + r;
            if (orow < M) C[(size_t)orow * 128 + ct * 16 + (l & 15)] = acc[ct][r];
        }
    }
}

// ---------- CSR aggregation: one wave per dst node; fused self-term + bias ----------
template <int SPLIT>
__global__ __launch_bounds__(256) void aggregate(const float* __restrict__ h,
                                                 const int* __restrict__ csr_src,
                                                 const int* __restrict__ rowptr,
                                                 const float* __restrict__ dis,
                                                 const float* __restrict__ bias,
                                                 float* __restrict__ out) {
    int wid = (blockIdx.x * 256 + threadIdx.x) >> 6;
    int lane = threadIdx.x & 63;
    if (wid >= N_NODES) return;
    int beg = rowptr[wid], end = rowptr[wid + 1];
    float dn = dis[wid];
    float2 self = ((const float2*)(h + (size_t)wid * 128))[lane];
    float2 bv = ((const float2*)bias)[lane];
    float sw = dn * dn;
    float2 acc;
    acc.x = self.x * sw + bv.x;
    acc.y = self.y * sw + bv.y;
    for (int c = beg; c < end; c += 64) {
        int idx = c + lane;
        int sl = (idx < end) ? csr_src[idx] : 0;
        float wl = (idx < end) ? dis[sl] * dn : 0.0f;
        int cnt = min(64, end - c);
        for (int j = 0; j < cnt; ++j) {
            int s = __shfl(sl, j);
            float w = __shfl(wl, j);
            float2 v = ((const float2*)(h + (size_t)s * 128))[lane];
            acc.x += v.x * w;
            acc.y += v.y * w;
        }
    }
    if (SPLIT == 0) {
        ((float2*)(out + (size_t)wid * 128))[lane] = acc;
    } else {
        int ch = lane * 2;
        size_t off = (ch < 64) ? ((size_t)wid * 64 + ch)
                               : ((size_t)(N_NODES + wid) * 64 + (ch - 64));
        *(float2*)(out + off) = acc;
    }
}

// ---------- batch norm ----------
__global__ void bn_stats(const float* __restrict__ hpre, float* __restrict__ stats) {
    int c = threadIdx.x & 127;
    int half = threadIdx.x >> 7;
    float s = 0.f, s2 = 0.f;
    int rpi = (blockDim.x >> 7) * gridDim.x;
    for (int n = blockIdx.x * 2 + half; n < N_NODES; n += rpi) {
        float v = hpre[(size_t)n * 128 + c];
        s += v; s2 += v * v;
    }
    __shared__ float ls[256], ls2[256];
    ls[threadIdx.x] = s; ls2[threadIdx.x] = s2;
    __syncthreads();
    if (threadIdx.x < 128) {
        s = ls[threadIdx.x] + ls[threadIdx.x + 128];
        s2 = ls2[threadIdx.x] + ls2[threadIdx.x + 128];
        atomicAdd(&stats[c], s);
        atomicAdd(&stats[128 + c], s2);
    }
}

__global__ void bn_finish(float* __restrict__ stats, const float* __restrict__ gamma,
                          const float* __restrict__ beta) {
    int c = threadIdx.x;
    if (c < 128) {
        float mean = stats[c] * (1.0f / N_NODES);
        float var = stats[128 + c] * (1.0f / N_NODES) - mean * mean;
        float scale = rsqrtf(var + BN_EPS) * gamma[c];
        stats[256 + c] = scale;
        stats[384 + c] = beta[c] - mean * scale;
    }
}

// BN + ReLU, emit bf16 rows (input to GEMM2)
__global__ void bn_relu_bf16(const float* __restrict__ hpre, const float* __restrict__ stats,
                             unsigned short* __restrict__ h1) {
    size_t t = (size_t)blockIdx.x * blockDim.x + threadIdx.x;  // 8-float units
    if (t >= (size_t)N_NODES * 16) return;
    int q = (int)(t & 15);
    const float4* src = (const float4*)hpre + t * 2;
    float4 v0 = src[0], v1 = src[1];
    const float4* scp = (const float4*)(stats + 256) + q * 2;
    const float4* shp = (const float4*)(stats + 384) + q * 2;
    float4 s0 = scp[0], s1 = scp[1], h0 = shp[0], h1v = shp[1];
    v8u o;
    o[0] = f2bf(fmaxf(v0.x * s0.x + h0.x, 0.f));
    o[1] = f2bf(fmaxf(v0.y * s0.y + h0.y, 0.f));
    o[2] = f2bf(fmaxf(v0.z * s0.z + h0.z, 0.f));
    o[3] = f2bf(fmaxf(v0.w * s0.w + h0.w, 0.f));
    o[4] = f2bf(fmaxf(v1.x * s1.x + h1v.x, 0.f));
    o[5] = f2bf(fmaxf(v1.y * s1.y + h1v.y, 0.f));
    o[6] = f2bf(fmaxf(v1.z * s1.z + h1v.z, 0.f));
    o[7] = f2bf(fmaxf(v1.w * s1.w + h1v.w, 0.f));
    *((v8u*)h1 + t) = o;
}

// ---------- concat W2|W3 -> Wcat[128,128], b2|b3 -> bcat[128] ----------
__global__ void build_wcat(const float* __restrict__ W2, const float* __restrict__ W3,
                           const float* __restrict__ b2, const float* __restrict__ b3,
                           float* __restrict__ Wcat, float* __restrict__ bcat) {
    int t = blockIdx.x * blockDim.x + threadIdx.x;
    if (t < 128 * 128) {
        int k = t >> 7, c = t & 127;
        Wcat[t] = (c < 64) ? W2[k * 64 + c] : W3[k * 64 + (c - 64)];
    }
    if (t < 128) bcat[t] = (t < 64) ? b2[t] : b3[t - 64];
}

extern "C" void kernel_launch(void* const* d_in, const int* in_sizes, int n_in,
                              void* d_out, int out_size, void* d_ws, size_t ws_size,
                              hipStream_t stream) {
    const float* x    = (const float*)d_in[0];
    const int* ei     = (const int*)d_in[1];
    const float* W1   = (const float*)d_in[2];
    const float* b1   = (const float*)d_in[3];
    const float* gamma= (const float*)d_in[4];
    const float* beta = (const float*)d_in[5];
    const float* W2   = (const float*)d_in[6];
    const float* b2   = (const float*)d_in[7];
    const float* W3   = (const float*)d_in[8];
    const float* b3   = (const float*)d_in[9];
    float* out = (float*)d_out;

    char* p = (char*)d_ws;
    auto alloc = [&](size_t bytes) {
        void* r = (void*)p;
        p += (bytes + 511) & ~(size_t)511;
        return r;
    };
    float* dis    = (float*)alloc(N_NODES * 4);
    int*   degi   = (int*)  alloc(N_NODES * 4);          // reused as cursor
    int*   rowptr = (int*)  alloc((N_NODES + 1) * 4);
    int*   part   = (int*)  alloc(2048);
    float* stats  = (float*)alloc(2048);
    int*   flag   = (int*)  alloc(256);
    float* Wcat   = (float*)alloc(128 * 128 * 4);
    float* bcat   = (float*)alloc(512);
    unsigned short* W1p   = (unsigned short*)alloc(256 * 128 * 2);
    unsigned short* Wcatp = (unsigned short*)alloc(128 * 128 * 2);
    int*   csrs   = (int*)  alloc((size_t)E_EDGES * 4);
    float* A      = (float*)alloc((size_t)N_NODES * 128 * 4);
    float* B      = (float*)alloc((size_t)N_NODES * 128 * 4);

    const int NB = (N_NODES + 255) / 256;  // 391
    const int GB = (N_NODES + 63) / 64;    // 1563

    hipMemsetAsync(degi, 0, N_NODES * 4, stream);
    hipMemsetAsync(stats, 0, 1024, stream);

    detect_dtype<<<1, 256, 0, stream>>>(ei, flag);
    deg_count<<<1024, 256, 0, stream>>>(ei, flag, degi);
    finish_dis<<<NB, 256, 0, stream>>>(degi, dis);

    // CSR build
    scan_phase1<<<NB, 256, 0, stream>>>(degi, rowptr, part);
    scan_phase2<<<1, 512, 0, stream>>>(part, NB);
    scan_phase3<<<NB, 256, 0, stream>>>(rowptr, part, degi /*cursor*/);
    csr_fill<<<1024, 256, 0, stream>>>(ei, flag, degi /*cursor*/, csrs);

    // weights: permute to b-frag order
    wperm<<<(256 * 128 + 255) / 256, 256, 0, stream>>>(W1, W1p, 256);
    build_wcat<<<64, 256, 0, stream>>>(W2, W3, b2, b3, Wcat, bcat);
    wperm<<<(128 * 128 + 255) / 256, 256, 0, stream>>>(Wcat, Wcatp, 128);

    // layer 1: h = x@W1 (MFMA) ; hpre = agg(h)+h*sw+b1 ; BN ; ReLU -> bf16
    gemm_mfma<IN_C, false><<<GB, 256, 0, stream>>>(x, W1p, A, N_NODES);
    aggregate<0><<<(N_NODES * 64 + 255) / 256, 256, 0, stream>>>(A, csrs, rowptr, dis, b1, B);
    bn_stats<<<512, 256, 0, stream>>>(B, stats);
    bn_finish<<<1, 128, 0, stream>>>(stats, gamma, beta);
    bn_relu_bf16<<<(N_NODES * 16 + 255) / 256, 256, 0, stream>>>(B, stats, (unsigned short*)A);

    // layer 2: t = h1@[W2|W3] (MFMA) ; out = agg(t)+t*sw+bcat
    gemm_mfma<HID_C, true><<<GB, 256, 0, stream>>>((unsigned short*)A, Wcatp, B, N_NODES);
    aggregate<1><<<(N_NODES * 64 + 255) / 256, 256, 0, stream>>>(B, csrs, rowptr, dis, bcat, out);
}

// Round 4
// 564.368 us; speedup vs baseline: 5.3857x; 1.0142x over previous
//
#include <hip/hip_runtime.h>

#define N_NODES 100000
#define E_EDGES 1600000
#define IN_C 256
#define HID_C 128
#define BN_EPS 1e-5f

#define DW_WBLOCKS 193   // weight-permute blocks in deg_and_weights
#define CSR_BLK 1024     // csr-fill blocks in csr_and_gemm1

using v8s = __attribute__((ext_vector_type(8))) short;
using v4f = __attribute__((ext_vector_type(4))) float;
using v8u = __attribute__((ext_vector_type(8))) unsigned short;

__device__ __forceinline__ unsigned short f2bf(float f) {
    unsigned int u = __float_as_uint(f);
    u += 0x7fffu + ((u >> 16) & 1u);
    return (unsigned short)(u >> 16);
}

// ---------- edge index accessors (int32 vs int64 detected at runtime) ----------
__device__ __forceinline__ int edge_src(const int* ei, int e, int is64) {
    return is64 ? ei[2 * e] : ei[e];
}
__device__ __forceinline__ int edge_dst(const int* ei, int e, int is64) {
    return is64 ? ei[2 * E_EDGES + 2 * e] : ei[E_EDGES + e];
}

__global__ void detect_dtype(const int* __restrict__ ei, int* __restrict__ flag) {
    __shared__ int any;
    if (threadIdx.x == 0) any = 0;
    __syncthreads();
    int v = 0;
    for (int i = threadIdx.x; i < 4096; i += blockDim.x) v |= ei[2 * i + 1];
    if (v) atomicOr(&any, 1);
    __syncthreads();
    if (threadIdx.x == 0) *flag = any ? 0 : 1;
}

// ---------- fused: degree histogram (blocks >= DW_WBLOCKS) + weight permute ----------
// W permute into B-frag order: ushort index t -> j=t&7, l=(t>>3)&63, ct=(t>>9)&7, kt=t>>12
//   k = kt*32 + (l>>4)*4 + (j&3) + 16*(j>>2),  n = ct*16 + (l&15)
__global__ void deg_and_weights(const int* __restrict__ ei, const int* __restrict__ flag,
                                int* __restrict__ degi,
                                const float* __restrict__ W1, const float* __restrict__ W2,
                                const float* __restrict__ W3, const float* __restrict__ b2,
                                const float* __restrict__ b3,
                                unsigned short* __restrict__ W1p,
                                unsigned short* __restrict__ Wcp,
                                float* __restrict__ bcat) {
    if (blockIdx.x < DW_WBLOCKS) {
        int t = blockIdx.x * 256 + threadIdx.x;
        if (t < 32768) {                       // W1p: K=256
            int j = t & 7, l = (t >> 3) & 63, ct = (t >> 9) & 7, kt = t >> 12;
            int k = kt * 32 + ((l >> 4) << 2) + (j & 3) + ((j >> 2) << 4);
            int n = ct * 16 + (l & 15);
            W1p[t] = f2bf(W1[k * 128 + n]);
        } else if (t < 49152) {                // Wcp: K=128, cols = [W2|W3]
            int u = t - 32768;
            int j = u & 7, l = (u >> 3) & 63, ct = (u >> 9) & 7, kt = u >> 12;
            int k = kt * 32 + ((l >> 4) << 2) + (j & 3) + ((j >> 2) << 4);
            int n = ct * 16 + (l & 15);
            float v = (n < 64) ? W2[k * 64 + n] : W3[k * 64 + (n - 64)];
            Wcp[u] = f2bf(v);
        } else if (t < 49280) {
            int c = t - 49152;
            bcat[c] = (c < 64) ? b2[c] : b3[c - 64];
        }
    } else {
        int is64 = *flag;
        int i = (blockIdx.x - DW_WBLOCKS) * 256 + threadIdx.x;
        int stride = 1024 * 256;
        for (int e = i; e < E_EDGES; e += stride)
            atomicAdd(&degi[edge_dst(ei, e, is64)], 1);
    }
}

// ---------- scan phase1 (+ fused dis = rsqrt(1+deg)) ----------
__global__ void scan_phase1(const int* __restrict__ degi, int* __restrict__ rowptr,
                            int* __restrict__ part, float* __restrict__ dis) {
    __shared__ int sh[256];
    int i = blockIdx.x * 256 + threadIdx.x;
    int v = (i < N_NODES) ? degi[i] : 0;
    if (i < N_NODES) dis[i] = rsqrtf(1.0f + (float)v);
    sh[threadIdx.x] = v;
    __syncthreads();
    for (int off = 1; off < 256; off <<= 1) {
        int t = (threadIdx.x >= off) ? sh[threadIdx.x - off] : 0;
        __syncthreads();
        sh[threadIdx.x] += t;
        __syncthreads();
    }
    if (i < N_NODES) rowptr[i] = sh[threadIdx.x] - v;
    if (threadIdx.x == 255) part[blockIdx.x] = sh[255];
}

__global__ void scan_phase2(int* __restrict__ part, int nb) {
    __shared__ int sh[512];
    int tid = threadIdx.x;
    int v = (tid < nb) ? part[tid] : 0;
    sh[tid] = v;
    __syncthreads();
    for (int off = 1; off < 512; off <<= 1) {
        int t = (tid >= off) ? sh[tid - off] : 0;
        __syncthreads();
        sh[tid] += t;
        __syncthreads();
    }
    if (tid < nb) part[tid] = sh[tid] - v;
}

__global__ void scan_phase3(int* __restrict__ rowptr, const int* __restrict__ part,
                            int* __restrict__ cursor) {
    int i = blockIdx.x * 256 + threadIdx.x;
    if (i < N_NODES) {
        int r = rowptr[i] + part[blockIdx.x];
        rowptr[i] = r;
        cursor[i] = r;
    }
    if (i == N_NODES - 1) rowptr[N_NODES] = E_EDGES;
}

// ---------- fused: csr_fill (blocks < CSR_BLK) || GEMM1 x@W1 -> bf16 ----------
__global__ __launch_bounds__(256) void csr_and_gemm1(
    const int* __restrict__ ei, const int* __restrict__ flag,
    int* __restrict__ cursor, int* __restrict__ csr_src,
    const float* __restrict__ x, const unsigned short* __restrict__ W1p,
    unsigned short* __restrict__ hbf) {
    if (blockIdx.x < CSR_BLK) {
        int is64 = *flag;
        int i = blockIdx.x * 256 + threadIdx.x;
        int stride = CSR_BLK * 256;
        for (int e = i; e < E_EDGES; e += stride) {
            int s = edge_src(ei, e, is64);
            int d = edge_dst(ei, e, is64);
            int pos = atomicAdd(&cursor[d], 1);
            csr_src[pos] = s;
        }
        return;
    }
    // ---- GEMM1 role: rows [bid*64, bid*64+64), fp32 input, bf16 output ----
    int bid = blockIdx.x - CSR_BLK;
    int wave = threadIdx.x >> 6;
    int l = threadIdx.x & 63;
    int kg = l >> 4;
    int row = bid * 64 + wave * 16 + (l & 15);
    int rl = min(row, N_NODES - 1);

    v4f acc[8];
    #pragma unroll
    for (int i = 0; i < 8; ++i)
        for (int r = 0; r < 4; ++r) acc[i][r] = 0.f;

    #pragma unroll
    for (int kt = 0; kt < IN_C / 32; ++kt) {
        v8s a;
        float4 u = *(const float4*)(x + (size_t)rl * IN_C + kt * 32 + kg * 4);
        float4 v = *(const float4*)(x + (size_t)rl * IN_C + kt * 32 + 16 + kg * 4);
        a[0] = f2bf(u.x); a[1] = f2bf(u.y); a[2] = f2bf(u.z); a[3] = f2bf(u.w);
        a[4] = f2bf(v.x); a[5] = f2bf(v.y); a[6] = f2bf(v.z); a[7] = f2bf(v.w);
        const v8s* bp = (const v8s*)W1p + (size_t)(kt * 8) * 64 + l;
        #pragma unroll
        for (int ct = 0; ct < 8; ++ct) {
            v8s b = bp[ct * 64];
            acc[ct] = __builtin_amdgcn_mfma_f32_16x16x32_bf16(a, b, acc[ct], 0, 0, 0);
        }
    }
    int orow0 = bid * 64 + wave * 16 + kg * 4;
    #pragma unroll
    for (int ct = 0; ct < 8; ++ct) {
        #pragma unroll
        for (int r = 0; r < 4; ++r) {
            int orow = orow0 + r;
            if (orow < N_NODES)
                hbf[(size_t)orow * 128 + ct * 16 + (l & 15)] = f2bf(acc[ct][r]);
        }
    }
}

// ---------- GEMM2: bf16 in, bf16 out ----------
__global__ __launch_bounds__(256) void gemm2_mfma(const unsigned short* __restrict__ A,
                                                  const unsigned short* __restrict__ Wp,
                                                  unsigned short* __restrict__ Cb) {
    int wave = threadIdx.x >> 6;
    int l = threadIdx.x & 63;
    int kg = l >> 4;
    int row = blockIdx.x * 64 + wave * 16 + (l & 15);
    int rl = min(row, N_NODES - 1);

    v4f acc[8];
    #pragma unroll
    for (int i = 0; i < 8; ++i)
        for (int r = 0; r < 4; ++r) acc[i][r] = 0.f;

    #pragma unroll
    for (int kt = 0; kt < HID_C / 32; ++kt) {
        union { struct { uint2 lo, hi; } q; v8s s; } u8;
        u8.q.lo = *(const uint2*)(A + (size_t)rl * HID_C + kt * 32 + kg * 4);
        u8.q.hi = *(const uint2*)(A + (size_t)rl * HID_C + kt * 32 + 16 + kg * 4);
        const v8s* bp = (const v8s*)Wp + (size_t)(kt * 8) * 64 + l;
        #pragma unroll
        for (int ct = 0; ct < 8; ++ct) {
            v8s b = bp[ct * 64];
            acc[ct] = __builtin_amdgcn_mfma_f32_16x16x32_bf16(u8.s, b, acc[ct], 0, 0, 0);
        }
    }
    int orow0 = blockIdx.x * 64 + wave * 16 + kg * 4;
    #pragma unroll
    for (int ct = 0; ct < 8; ++ct) {
        #pragma unroll
        for (int r = 0; r < 4; ++r) {
            int orow = orow0 + r;
            if (orow < N_NODES)
                Cb[(size_t)orow * 128 + ct * 16 + (l & 15)] = f2bf(acc[ct][r]);
        }
    }
}

// ---------- CSR aggregation over bf16 table; fused self-term + bias; fp32 out ----------
template <int SPLIT>
__global__ __launch_bounds__(256) void aggregate_bf16(const unsigned int* __restrict__ hb,
                                                      const int* __restrict__ csr_src,
                                                      const int* __restrict__ rowptr,
                                                      const float* __restrict__ dis,
                                                      const float* __restrict__ bias,
                                                      float* __restrict__ out) {
    int wid = (blockIdx.x * 256 + threadIdx.x) >> 6;
    int lane = threadIdx.x & 63;
    if (wid >= N_NODES) return;
    int beg = rowptr[wid], end = rowptr[wid + 1];
    float dn = dis[wid];
    unsigned int su = hb[(size_t)wid * 64 + lane];
    float2 bv = ((const float2*)bias)[lane];
    float sw = dn * dn;
    float ax = __uint_as_float(su << 16) * sw + bv.x;
    float ay = __uint_as_float(su & 0xffff0000u) * sw + bv.y;
    for (int c = beg; c < end; c += 64) {
        int idx = c + lane;
        int sl = (idx < end) ? csr_src[idx] : 0;
        float wl = (idx < end) ? dis[sl] * dn : 0.0f;
        int cnt = min(64, end - c);
        for (int j = 0; j < cnt; ++j) {
            int s = __shfl(sl, j);
            float w = __shfl(wl, j);
            unsigned int u = hb[(size_t)s * 64 + lane];
            ax += __uint_as_float(u << 16) * w;
            ay += __uint_as_float(u & 0xffff0000u) * w;
        }
    }
    if (SPLIT == 0) {
        float2 o = {ax, ay};
        ((float2*)(out + (size_t)wid * 128))[lane] = o;
    } else {
        int ch = lane * 2;
        size_t off = (ch < 64) ? ((size_t)wid * 64 + ch)
                               : ((size_t)(N_NODES + wid) * 64 + (ch - 64));
        float2 o = {ax, ay};
        *(float2*)(out + off) = o;
    }
}

// ---------- batch norm ----------
__global__ void bn_stats(const float* __restrict__ hpre, float* __restrict__ stats) {
    int c = threadIdx.x & 127;
    int half = threadIdx.x >> 7;
    float s = 0.f, s2 = 0.f;
    int rpi = (blockDim.x >> 7) * gridDim.x;
    for (int n = blockIdx.x * 2 + half; n < N_NODES; n += rpi) {
        float v = hpre[(size_t)n * 128 + c];
        s += v; s2 += v * v;
    }
    __shared__ float ls[256], ls2[256];
    ls[threadIdx.x] = s; ls2[threadIdx.x] = s2;
    __syncthreads();
    if (threadIdx.x < 128) {
        s = ls[threadIdx.x] + ls[threadIdx.x + 128];
        s2 = ls2[threadIdx.x] + ls2[threadIdx.x + 128];
        atomicAdd(&stats[c], s);
        atomicAdd(&stats[128 + c], s2);
    }
}

__global__ void bn_finish(float* __restrict__ stats, const float* __restrict__ gamma,
                          const float* __restrict__ beta) {
    int c = threadIdx.x;
    if (c < 128) {
        float mean = stats[c] * (1.0f / N_NODES);
        float var = stats[128 + c] * (1.0f / N_NODES) - mean * mean;
        float scale = rsqrtf(var + BN_EPS) * gamma[c];
        stats[256 + c] = scale;
        stats[384 + c] = beta[c] - mean * scale;
    }
}

// BN + ReLU, emit bf16 rows (input to GEMM2)
__global__ void bn_relu_bf16(const float* __restrict__ hpre, const float* __restrict__ stats,
                             unsigned short* __restrict__ h1) {
    size_t t = (size_t)blockIdx.x * blockDim.x + threadIdx.x;  // 8-float units
    if (t >= (size_t)N_NODES * 16) return;
    int q = (int)(t & 15);
    const float4* src = (const float4*)hpre + t * 2;
    float4 v0 = src[0], v1 = src[1];
    const float4* scp = (const float4*)(stats + 256) + q * 2;
    const float4* shp = (const float4*)(stats + 384) + q * 2;
    float4 s0 = scp[0], s1 = scp[1], h0 = shp[0], h1v = shp[1];
    v8u o;
    o[0] = f2bf(fmaxf(v0.x * s0.x + h0.x, 0.f));
    o[1] = f2bf(fmaxf(v0.y * s0.y + h0.y, 0.f));
    o[2] = f2bf(fmaxf(v0.z * s0.z + h0.z, 0.f));
    o[3] = f2bf(fmaxf(v0.w * s0.w + h0.w, 0.f));
    o[4] = f2bf(fmaxf(v1.x * s1.x + h1v.x, 0.f));
    o[5] = f2bf(fmaxf(v1.y * s1.y + h1v.y, 0.f));
    o[6] = f2bf(fmaxf(v1.z * s1.z + h1v.z, 0.f));
    o[7] = f2bf(fmaxf(v1.w * s1.w + h1v.w, 0.f));
    *((v8u*)h1 + t) = o;
}

extern "C" void kernel_launch(void* const* d_in, const int* in_sizes, int n_in,
                              void* d_out, int out_size, void* d_ws, size_t ws_size,
                              hipStream_t stream) {
    const float* x    = (const float*)d_in[0];
    const int* ei     = (const int*)d_in[1];
    const float* W1   = (const float*)d_in[2];
    const float* b1   = (const float*)d_in[3];
    const float* gamma= (const float*)d_in[4];
    const float* beta = (const float*)d_in[5];
    const float* W2   = (const float*)d_in[6];
    const float* b2   = (const float*)d_in[7];
    const float* W3   = (const float*)d_in[8];
    const float* b3   = (const float*)d_in[9];
    float* out = (float*)d_out;

    char* p = (char*)d_ws;
    auto alloc = [&](size_t bytes) {
        void* r = (void*)p;
        p += (bytes + 511) & ~(size_t)511;
        return r;
    };
    float* dis    = (float*)alloc(N_NODES * 4);
    int*   degi   = (int*)  alloc(N_NODES * 4);          // reused as cursor
    int*   rowptr = (int*)  alloc((N_NODES + 1) * 4);
    int*   part   = (int*)  alloc(2048);
    float* stats  = (float*)alloc(2048);
    int*   flag   = (int*)  alloc(256);
    float* bcat   = (float*)alloc(512);
    unsigned short* W1p = (unsigned short*)alloc(256 * 128 * 2);
    unsigned short* Wcp = (unsigned short*)alloc(128 * 128 * 2);
    int*   csrs   = (int*)  alloc((size_t)E_EDGES * 4);
    unsigned short* hbf  = (unsigned short*)alloc((size_t)N_NODES * 128 * 2);  // h bf16 / h1 bf16
    float* hpre   = (float*)alloc((size_t)N_NODES * 128 * 4);                  // agg1 out / t bf16 alias
    unsigned short* tbf = (unsigned short*)hpre;  // gemm2 out aliases hpre (dead by then)

    const int NB = (N_NODES + 255) / 256;  // 391
    const int GB = (N_NODES + 63) / 64;    // 1563

    hipMemsetAsync(degi, 0, N_NODES * 4, stream);
    hipMemsetAsync(stats, 0, 1024, stream);

    detect_dtype<<<1, 256, 0, stream>>>(ei, flag);
    // degree histogram || weight permutes
    deg_and_weights<<<DW_WBLOCKS + 1024, 256, 0, stream>>>(ei, flag, degi, W1, W2, W3,
                                                           b2, b3, W1p, Wcp, bcat);
    // rowptr scan (+dis)
    scan_phase1<<<NB, 256, 0, stream>>>(degi, rowptr, part, dis);
    scan_phase2<<<1, 512, 0, stream>>>(part, NB);
    scan_phase3<<<NB, 256, 0, stream>>>(rowptr, part, degi /*cursor*/);

    // csr fill || gemm1 (independent)
    csr_and_gemm1<<<CSR_BLK + GB, 256, 0, stream>>>(ei, flag, degi /*cursor*/, csrs,
                                                    x, W1p, hbf);

    // layer 1 aggregate + BN + ReLU
    aggregate_bf16<0><<<(N_NODES * 64 + 255) / 256, 256, 0, stream>>>(
        (const unsigned int*)hbf, csrs, rowptr, dis, b1, hpre);
    bn_stats<<<512, 256, 0, stream>>>(hpre, stats);
    bn_finish<<<1, 128, 0, stream>>>(stats, gamma, beta);
    bn_relu_bf16<<<(N_NODES * 16 + 255) / 256, 256, 0, stream>>>(hpre, stats, hbf);

    // layer 2
    gemm2_mfma<<<GB, 256, 0, stream>>>(hbf, Wcp, tbf);
    aggregate_bf16<1><<<(N_NODES * 64 + 255) / 256, 256, 0, stream>>>(
        (const unsigned int*)tbf, csrs, rowptr, dis, bcat, out);
}

// Round 5
// 402.919 us; speedup vs baseline: 7.5438x; 1.4007x over previous
//
#include <hip/hip_runtime.h>

#define N_NODES 100000
#define E_EDGES 1600000
#define IN_C 256
#define HID_C 128
#define BN_EPS 1e-5f

#define DW_WBLOCKS 193   // weight-permute blocks in deg_and_weights
#define CSR_BLK 1024     // csr-fill blocks in csr_and_gemm1

using v8s = __attribute__((ext_vector_type(8))) short;
using v4f = __attribute__((ext_vector_type(4))) float;

__device__ __forceinline__ unsigned short f2bf(float f) {
    unsigned int u = __float_as_uint(f);
    u += 0x7fffu + ((u >> 16) & 1u);
    return (unsigned short)(u >> 16);
}

// ---------- edge index accessors (int32 vs int64 detected at runtime) ----------
__device__ __forceinline__ int edge_src(const int* ei, int e, int is64) {
    return is64 ? ei[2 * e] : ei[e];
}
__device__ __forceinline__ int edge_dst(const int* ei, int e, int is64) {
    return is64 ? ei[2 * E_EDGES + 2 * e] : ei[E_EDGES + e];
}

__global__ void detect_dtype(const int* __restrict__ ei, int* __restrict__ flag) {
    __shared__ int any;
    if (threadIdx.x == 0) any = 0;
    __syncthreads();
    int v = 0;
    for (int i = threadIdx.x; i < 4096; i += blockDim.x) v |= ei[2 * i + 1];
    if (v) atomicOr(&any, 1);
    __syncthreads();
    if (threadIdx.x == 0) *flag = any ? 0 : 1;
}

// ---------- fused: degree histogram (blocks >= DW_WBLOCKS) + weight permute ----------
__global__ void deg_and_weights(const int* __restrict__ ei, const int* __restrict__ flag,
                                int* __restrict__ degi,
                                const float* __restrict__ W1, const float* __restrict__ W2,
                                const float* __restrict__ W3, const float* __restrict__ b2,
                                const float* __restrict__ b3,
                                unsigned short* __restrict__ W1p,
                                unsigned short* __restrict__ Wcp,
                                float* __restrict__ bcat) {
    if (blockIdx.x < DW_WBLOCKS) {
        int t = blockIdx.x * 256 + threadIdx.x;
        if (t < 32768) {                       // W1p: K=256
            int j = t & 7, l = (t >> 3) & 63, ct = (t >> 9) & 7, kt = t >> 12;
            int k = kt * 32 + ((l >> 4) << 2) + (j & 3) + ((j >> 2) << 4);
            int n = ct * 16 + (l & 15);
            W1p[t] = f2bf(W1[k * 128 + n]);
        } else if (t < 49152) {                // Wcp: K=128, cols = [W2|W3]
            int u = t - 32768;
            int j = u & 7, l = (u >> 3) & 63, ct = (u >> 9) & 7, kt = u >> 12;
            int k = kt * 32 + ((l >> 4) << 2) + (j & 3) + ((j >> 2) << 4);
            int n = ct * 16 + (l & 15);
            float v = (n < 64) ? W2[k * 64 + n] : W3[k * 64 + (n - 64)];
            Wcp[u] = f2bf(v);
        } else if (t < 49280) {
            int c = t - 49152;
            bcat[c] = (c < 64) ? b2[c] : b3[c - 64];
        }
    } else {
        int is64 = *flag;
        int i = (blockIdx.x - DW_WBLOCKS) * 256 + threadIdx.x;
        int stride = 1024 * 256;
        for (int e = i; e < E_EDGES; e += stride)
            atomicAdd(&degi[edge_dst(ei, e, is64)], 1);
    }
}

// ---------- scan phase1 (+ fused dis = rsqrt(1+deg)) ----------
__global__ void scan_phase1(const int* __restrict__ degi, int* __restrict__ rowptr,
                            int* __restrict__ part, float* __restrict__ dis) {
    __shared__ int sh[256];
    int i = blockIdx.x * 256 + threadIdx.x;
    int v = (i < N_NODES) ? degi[i] : 0;
    if (i < N_NODES) dis[i] = rsqrtf(1.0f + (float)v);
    sh[threadIdx.x] = v;
    __syncthreads();
    for (int off = 1; off < 256; off <<= 1) {
        int t = (threadIdx.x >= off) ? sh[threadIdx.x - off] : 0;
        __syncthreads();
        sh[threadIdx.x] += t;
        __syncthreads();
    }
    if (i < N_NODES) rowptr[i] = sh[threadIdx.x] - v;
    if (threadIdx.x == 255) part[blockIdx.x] = sh[255];
}

__global__ void scan_phase2(int* __restrict__ part, int nb) {
    __shared__ int sh[512];
    int tid = threadIdx.x;
    int v = (tid < nb) ? part[tid] : 0;
    sh[tid] = v;
    __syncthreads();
    for (int off = 1; off < 512; off <<= 1) {
        int t = (tid >= off) ? sh[tid - off] : 0;
        __syncthreads();
        sh[tid] += t;
        __syncthreads();
    }
    if (tid < nb) part[tid] = sh[tid] - v;
}

__global__ void scan_phase3(int* __restrict__ rowptr, const int* __restrict__ part,
                            int* __restrict__ cursor) {
    int i = blockIdx.x * 256 + threadIdx.x;
    if (i < N_NODES) {
        int r = rowptr[i] + part[blockIdx.x];
        rowptr[i] = r;
        cursor[i] = r;
    }
    if (i == N_NODES - 1) rowptr[N_NODES] = E_EDGES;
}

// ---------- fused: batched csr_fill (blocks < CSR_BLK) || GEMM1 x@W1 -> bf16 ----------
__global__ __launch_bounds__(256) void csr_and_gemm1(
    const int* __restrict__ ei, const int* __restrict__ flag,
    int* __restrict__ cursor, int* __restrict__ csr_src,
    const float* __restrict__ x, const unsigned short* __restrict__ W1p,
    unsigned short* __restrict__ hbf) {
    if (blockIdx.x < CSR_BLK) {
        // 7 independent edges per thread: all loads, then all atomics (in flight
        // together), then all stores. Breaks the atomic round-trip dependency.
        int is64 = *flag;
        int tid = blockIdx.x * 256 + threadIdx.x;
        const int T = CSR_BLK * 256;                    // 262144
        int s[7], d[7], pos[7];
        #pragma unroll
        for (int i = 0; i < 7; ++i) {
            int e = tid + i * T;
            bool ok = (e < E_EDGES);
            s[i] = ok ? edge_src(ei, e, is64) : -1;
            d[i] = ok ? edge_dst(ei, e, is64) : 0;
        }
        #pragma unroll
        for (int i = 0; i < 7; ++i)
            pos[i] = (s[i] >= 0) ? atomicAdd(&cursor[d[i]], 1) : 0;
        #pragma unroll
        for (int i = 0; i < 7; ++i)
            if (s[i] >= 0) csr_src[pos[i]] = s[i];
        return;
    }
    // ---- GEMM1 role: rows [bid*64, bid*64+64), fp32 input, bf16 output ----
    int bid = blockIdx.x - CSR_BLK;
    int wave = threadIdx.x >> 6;
    int l = threadIdx.x & 63;
    int kg = l >> 4;
    int row = bid * 64 + wave * 16 + (l & 15);
    int rl = min(row, N_NODES - 1);

    v4f acc[8];
    #pragma unroll
    for (int i = 0; i < 8; ++i)
        for (int r = 0; r < 4; ++r) acc[i][r] = 0.f;

    #pragma unroll
    for (int kt = 0; kt < IN_C / 32; ++kt) {
        v8s a;
        float4 u = *(const float4*)(x + (size_t)rl * IN_C + kt * 32 + kg * 4);
        float4 v = *(const float4*)(x + (size_t)rl * IN_C + kt * 32 + 16 + kg * 4);
        a[0] = f2bf(u.x); a[1] = f2bf(u.y); a[2] = f2bf(u.z); a[3] = f2bf(u.w);
        a[4] = f2bf(v.x); a[5] = f2bf(v.y); a[6] = f2bf(v.z); a[7] = f2bf(v.w);
        const v8s* bp = (const v8s*)W1p + (size_t)(kt * 8) * 64 + l;
        #pragma unroll
        for (int ct = 0; ct < 8; ++ct) {
            v8s b = bp[ct * 64];
            acc[ct] = __builtin_amdgcn_mfma_f32_16x16x32_bf16(a, b, acc[ct], 0, 0, 0);
        }
    }
    int orow0 = bid * 64 + wave * 16 + kg * 4;
    #pragma unroll
    for (int ct = 0; ct < 8; ++ct) {
        #pragma unroll
        for (int r = 0; r < 4; ++r) {
            int orow = orow0 + r;
            if (orow < N_NODES)
                hbf[(size_t)orow * 128 + ct * 16 + (l & 15)] = f2bf(acc[ct][r]);
        }
    }
}

// ---------- GEMM2 with fused BN+ReLU on the A operand: reads hpre fp32 + stats ----------
__global__ __launch_bounds__(256) void gemm2_bn_mfma(const float* __restrict__ hpre,
                                                     const float* __restrict__ stats,
                                                     const unsigned short* __restrict__ Wp,
                                                     unsigned short* __restrict__ Cb) {
    int wave = threadIdx.x >> 6;
    int l = threadIdx.x & 63;
    int kg = l >> 4;
    int row = blockIdx.x * 64 + wave * 16 + (l & 15);
    int rl = min(row, N_NODES - 1);

    v4f acc[8];
    #pragma unroll
    for (int i = 0; i < 8; ++i)
        for (int r = 0; r < 4; ++r) acc[i][r] = 0.f;

    #pragma unroll
    for (int kt = 0; kt < HID_C / 32; ++kt) {
        int k0 = kt * 32 + kg * 4;
        float4 u  = *(const float4*)(hpre + (size_t)rl * HID_C + k0);
        float4 v  = *(const float4*)(hpre + (size_t)rl * HID_C + k0 + 16);
        float4 sc0 = *(const float4*)(stats + 256 + k0);
        float4 sh0 = *(const float4*)(stats + 384 + k0);
        float4 sc1 = *(const float4*)(stats + 256 + k0 + 16);
        float4 sh1 = *(const float4*)(stats + 384 + k0 + 16);
        v8s a;
        a[0] = f2bf(fmaxf(u.x * sc0.x + sh0.x, 0.f));
        a[1] = f2bf(fmaxf(u.y * sc0.y + sh0.y, 0.f));
        a[2] = f2bf(fmaxf(u.z * sc0.z + sh0.z, 0.f));
        a[3] = f2bf(fmaxf(u.w * sc0.w + sh0.w, 0.f));
        a[4] = f2bf(fmaxf(v.x * sc1.x + sh1.x, 0.f));
        a[5] = f2bf(fmaxf(v.y * sc1.y + sh1.y, 0.f));
        a[6] = f2bf(fmaxf(v.z * sc1.z + sh1.z, 0.f));
        a[7] = f2bf(fmaxf(v.w * sc1.w + sh1.w, 0.f));
        const v8s* bp = (const v8s*)Wp + (size_t)(kt * 8) * 64 + l;
        #pragma unroll
        for (int ct = 0; ct < 8; ++ct) {
            v8s b = bp[ct * 64];
            acc[ct] = __builtin_amdgcn_mfma_f32_16x16x32_bf16(a, b, acc[ct], 0, 0, 0);
        }
    }
    int orow0 = blockIdx.x * 64 + wave * 16 + kg * 4;
    #pragma unroll
    for (int ct = 0; ct < 8; ++ct) {
        #pragma unroll
        for (int r = 0; r < 4; ++r) {
            int orow = orow0 + r;
            if (orow < N_NODES)
                Cb[(size_t)orow * 128 + ct * 16 + (l & 15)] = f2bf(acc[ct][r]);
        }
    }
}

// ---------- CSR aggregation, unroll-8 independent gathers ----------
template <int SPLIT>
__global__ __launch_bounds__(256) void aggregate_bf16(const unsigned int* __restrict__ hb,
                                                      const int* __restrict__ csr_src,
                                                      const int* __restrict__ rowptr,
                                                      const float* __restrict__ dis,
                                                      const float* __restrict__ bias,
                                                      float* __restrict__ out) {
    int wid = (blockIdx.x * 256 + threadIdx.x) >> 6;
    int lane = threadIdx.x & 63;
    if (wid >= N_NODES) return;
    int beg = rowptr[wid], end = rowptr[wid + 1];
    float dn = dis[wid];
    unsigned int su = hb[(size_t)wid * 64 + lane];
    float2 bv = ((const float2*)bias)[lane];
    float sw = dn * dn;
    float ax = __uint_as_float(su << 16) * sw + bv.x;
    float ay = __uint_as_float(su & 0xffff0000u) * sw + bv.y;
    for (int c = beg; c < end; c += 64) {
        int idx = c + lane;
        int sl = (idx < end) ? csr_src[idx] : 0;
        float wl = (idx < end) ? dis[sl] * dn : 0.0f;
        int cnt = min(64, end - c);
        // unroll-8: padded lanes carry wl=0 and sl=0, so over-reads add 0
        for (int j = 0; j < cnt; j += 8) {
            int s0 = __shfl(sl, j + 0), s1 = __shfl(sl, j + 1);
            int s2 = __shfl(sl, j + 2), s3 = __shfl(sl, j + 3);
            int s4 = __shfl(sl, j + 4), s5 = __shfl(sl, j + 5);
            int s6 = __shfl(sl, j + 6), s7 = __shfl(sl, j + 7);
            float w0 = __shfl(wl, j + 0), w1 = __shfl(wl, j + 1);
            float w2 = __shfl(wl, j + 2), w3 = __shfl(wl, j + 3);
            float w4 = __shfl(wl, j + 4), w5 = __shfl(wl, j + 5);
            float w6 = __shfl(wl, j + 6), w7 = __shfl(wl, j + 7);
            unsigned int u0 = hb[(size_t)s0 * 64 + lane];
            unsigned int u1 = hb[(size_t)s1 * 64 + lane];
            unsigned int u2 = hb[(size_t)s2 * 64 + lane];
            unsigned int u3 = hb[(size_t)s3 * 64 + lane];
            unsigned int u4 = hb[(size_t)s4 * 64 + lane];
            unsigned int u5 = hb[(size_t)s5 * 64 + lane];
            unsigned int u6 = hb[(size_t)s6 * 64 + lane];
            unsigned int u7 = hb[(size_t)s7 * 64 + lane];
            ax += __uint_as_float(u0 << 16) * w0; ay += __uint_as_float(u0 & 0xffff0000u) * w0;
            ax += __uint_as_float(u1 << 16) * w1; ay += __uint_as_float(u1 & 0xffff0000u) * w1;
            ax += __uint_as_float(u2 << 16) * w2; ay += __uint_as_float(u2 & 0xffff0000u) * w2;
            ax += __uint_as_float(u3 << 16) * w3; ay += __uint_as_float(u3 & 0xffff0000u) * w3;
            ax += __uint_as_float(u4 << 16) * w4; ay += __uint_as_float(u4 & 0xffff0000u) * w4;
            ax += __uint_as_float(u5 << 16) * w5; ay += __uint_as_float(u5 & 0xffff0000u) * w5;
            ax += __uint_as_float(u6 << 16) * w6; ay += __uint_as_float(u6 & 0xffff0000u) * w6;
            ax += __uint_as_float(u7 << 16) * w7; ay += __uint_as_float(u7 & 0xffff0000u) * w7;
        }
    }
    if (SPLIT == 0) {
        float2 o = {ax, ay};
        ((float2*)(out + (size_t)wid * 128))[lane] = o;
    } else {
        int ch = lane * 2;
        size_t off = (ch < 64) ? ((size_t)wid * 64 + ch)
                               : ((size_t)(N_NODES + wid) * 64 + (ch - 64));
        float2 o = {ax, ay};
        *(float2*)(out + off) = o;
    }
}

// ---------- batch norm stats ----------
__global__ void bn_stats(const float* __restrict__ hpre, float* __restrict__ stats) {
    int c = threadIdx.x & 127;
    int half = threadIdx.x >> 7;
    float s = 0.f, s2 = 0.f;
    int rpi = (blockDim.x >> 7) * gridDim.x;
    for (int n = blockIdx.x * 2 + half; n < N_NODES; n += rpi) {
        float v = hpre[(size_t)n * 128 + c];
        s += v; s2 += v * v;
    }
    __shared__ float ls[256], ls2[256];
    ls[threadIdx.x] = s; ls2[threadIdx.x] = s2;
    __syncthreads();
    if (threadIdx.x < 128) {
        s = ls[threadIdx.x] + ls[threadIdx.x + 128];
        s2 = ls2[threadIdx.x] + ls2[threadIdx.x + 128];
        atomicAdd(&stats[c], s);
        atomicAdd(&stats[128 + c], s2);
    }
}

__global__ void bn_finish(float* __restrict__ stats, const float* __restrict__ gamma,
                          const float* __restrict__ beta) {
    int c = threadIdx.x;
    if (c < 128) {
        float mean = stats[c] * (1.0f / N_NODES);
        float var = stats[128 + c] * (1.0f / N_NODES) - mean * mean;
        float scale = rsqrtf(var + BN_EPS) * gamma[c];
        stats[256 + c] = scale;
        stats[384 + c] = beta[c] - mean * scale;
    }
}

extern "C" void kernel_launch(void* const* d_in, const int* in_sizes, int n_in,
                              void* d_out, int out_size, void* d_ws, size_t ws_size,
                              hipStream_t stream) {
    const float* x    = (const float*)d_in[0];
    const int* ei     = (const int*)d_in[1];
    const float* W1   = (const float*)d_in[2];
    const float* b1   = (const float*)d_in[3];
    const float* gamma= (const float*)d_in[4];
    const float* beta = (const float*)d_in[5];
    const float* W2   = (const float*)d_in[6];
    const float* b2   = (const float*)d_in[7];
    const float* W3   = (const float*)d_in[8];
    const float* b3   = (const float*)d_in[9];
    float* out = (float*)d_out;

    char* p = (char*)d_ws;
    auto alloc = [&](size_t bytes) {
        void* r = (void*)p;
        p += (bytes + 511) & ~(size_t)511;
        return r;
    };
    float* dis    = (float*)alloc(N_NODES * 4);
    int*   degi   = (int*)  alloc(N_NODES * 4);          // reused as cursor
    int*   rowptr = (int*)  alloc((N_NODES + 1) * 4);
    int*   part   = (int*)  alloc(2048);
    float* stats  = (float*)alloc(2048);
    int*   flag   = (int*)  alloc(256);
    float* bcat   = (float*)alloc(512);
    unsigned short* W1p = (unsigned short*)alloc(256 * 128 * 2);
    unsigned short* Wcp = (unsigned short*)alloc(128 * 128 * 2);
    int*   csrs   = (int*)  alloc((size_t)E_EDGES * 4);
    unsigned short* hbf  = (unsigned short*)alloc((size_t)N_NODES * 128 * 2);  // gemm1 out / gemm2 out
    float* hpre   = (float*)alloc((size_t)N_NODES * 128 * 4);                  // agg1 out (BN input)

    const int NB = (N_NODES + 255) / 256;  // 391
    const int GB = (N_NODES + 63) / 64;    // 1563

    hipMemsetAsync(degi, 0, N_NODES * 4, stream);
    hipMemsetAsync(stats, 0, 1024, stream);

    detect_dtype<<<1, 256, 0, stream>>>(ei, flag);
    // degree histogram || weight permutes
    deg_and_weights<<<DW_WBLOCKS + 1024, 256, 0, stream>>>(ei, flag, degi, W1, W2, W3,
                                                           b2, b3, W1p, Wcp, bcat);
    // rowptr scan (+dis)
    scan_phase1<<<NB, 256, 0, stream>>>(degi, rowptr, part, dis);
    scan_phase2<<<1, 512, 0, stream>>>(part, NB);
    scan_phase3<<<NB, 256, 0, stream>>>(rowptr, part, degi /*cursor*/);

    // csr fill (batched atomics) || gemm1
    csr_and_gemm1<<<CSR_BLK + GB, 256, 0, stream>>>(ei, flag, degi /*cursor*/, csrs,
                                                    x, W1p, hbf);

    // layer 1 aggregate + BN stats
    aggregate_bf16<0><<<(N_NODES * 64 + 255) / 256, 256, 0, stream>>>(
        (const unsigned int*)hbf, csrs, rowptr, dis, b1, hpre);
    bn_stats<<<512, 256, 0, stream>>>(hpre, stats);
    bn_finish<<<1, 128, 0, stream>>>(stats, gamma, beta);

    // layer 2: BN+ReLU fused into GEMM2's A-load; output bf16 into hbf (dead)
    gemm2_bn_mfma<<<GB, 256, 0, stream>>>(hpre, stats, Wcp, hbf);
    aggregate_bf16<1><<<(N_NODES * 64 + 255) / 256, 256, 0, stream>>>(
        (const unsigned int*)hbf, csrs, rowptr, dis, bcat, out);
}

// Round 6
// 301.913 us; speedup vs baseline: 10.0676x; 1.3346x over previous
//
#include <hip/hip_runtime.h>

#define N_NODES 100000
#define E_EDGES 1600000
#define IN_C 256
#define HID_C 128
#define BN_EPS 1e-5f

#define NBUCK 391                      // buckets of 256 nodes: dst >> 8
#define BIN_BLOCKS 256
#define CHUNK (E_EDGES / BIN_BLOCKS)   // 6250
#define HW 392                         // segment-table row width (incl. sentinel)

using v8s = __attribute__((ext_vector_type(8))) short;
using v4f = __attribute__((ext_vector_type(4))) float;

__device__ __forceinline__ unsigned short f2bf(float f) {
    unsigned int u = __float_as_uint(f);
    u += 0x7fffu + ((u >> 16) & 1u);
    return (unsigned short)(u >> 16);
}

// ---------- edge index accessors (int32 vs int64 detected at runtime) ----------
__device__ __forceinline__ int edge_src(const int* ei, int e, int is64) {
    return is64 ? ei[2 * e] : ei[e];
}
__device__ __forceinline__ int edge_dst(const int* ei, int e, int is64) {
    return is64 ? ei[2 * E_EDGES + 2 * e] : ei[E_EDGES + e];
}

// ---------- prep: dtype detect (block 0) + weight permutes (blocks 1..193) ----------
__global__ void prep_kernel(const int* __restrict__ ei, int* __restrict__ flag,
                            const float* __restrict__ W1, const float* __restrict__ W2,
                            const float* __restrict__ W3, const float* __restrict__ b2,
                            const float* __restrict__ b3,
                            unsigned short* __restrict__ W1p,
                            unsigned short* __restrict__ Wcp,
                            float* __restrict__ bcat) {
    __shared__ int any;
    if (blockIdx.x == 0) {
        if (threadIdx.x == 0) any = 0;
        __syncthreads();
        int v = 0;
        for (int i = threadIdx.x; i < 4096; i += blockDim.x) v |= ei[2 * i + 1];
        if (v) atomicOr(&any, 1);
        __syncthreads();
        if (threadIdx.x == 0) *flag = any ? 0 : 1;
        return;
    }
    int t = (blockIdx.x - 1) * 256 + threadIdx.x;
    if (t < 32768) {                       // W1p: K=256
        int j = t & 7, l = (t >> 3) & 63, ct = (t >> 9) & 7, kt = t >> 12;
        int k = kt * 32 + ((l >> 4) << 2) + (j & 3) + ((j >> 2) << 4);
        int n = ct * 16 + (l & 15);
        W1p[t] = f2bf(W1[k * 128 + n]);
    } else if (t < 49152) {                // Wcp: K=128, cols = [W2|W3]
        int u = t - 32768;
        int j = u & 7, l = (u >> 3) & 63, ct = (u >> 9) & 7, kt = u >> 12;
        int k = kt * 32 + ((l >> 4) << 2) + (j & 3) + ((j >> 2) << 4);
        int n = ct * 16 + (l & 15);
        float v = (n < 64) ? W2[k * 64 + n] : W3[k * 64 + (n - 64)];
        Wcp[u] = f2bf(v);
    } else if (t < 49280) {
        int c = t - 49152;
        bcat[c] = (c < 64) ? b2[c] : b3[c - 64];
    }
}

// ---------- fused: per-block counting sort of edges by dst-bucket || GEMM1 ----------
// bin role (blocks < BIN_BLOCKS): chunk of 6250 edges -> LDS hist -> LDS scan ->
// H[blk][b] segment offsets -> scatter packed (src<<8|dstLow) into private region.
__global__ __launch_bounds__(256) void bin_and_gemm1(
    const int* __restrict__ ei, const int* __restrict__ flag,
    unsigned int* __restrict__ ebuf, int* __restrict__ H,
    const float* __restrict__ x, const unsigned short* __restrict__ W1p,
    unsigned short* __restrict__ hbf) {
    __shared__ int sh[512];
    __shared__ int cur[HW];
    if (blockIdx.x < BIN_BLOCKS) {
        int tid = threadIdx.x;
        int is64 = *flag;
        int base = blockIdx.x * CHUNK;
        sh[tid] = 0; sh[tid + 256] = 0;
        __syncthreads();
        for (int i = tid; i < CHUNK; i += 256) {
            int d = edge_dst(ei, base + i, is64);
            atomicAdd(&sh[d >> 8], 1);
        }
        __syncthreads();
        // Hillis-Steele inclusive scan over 512 slots with 256 threads
        int t0 = tid, t1 = tid + 256;
        int c0 = sh[t0], c1 = sh[t1];
        for (int off = 1; off < 512; off <<= 1) {
            int a0 = (t0 >= off) ? sh[t0 - off] : 0;
            int a1 = (t1 >= off) ? sh[t1 - off] : 0;
            __syncthreads();
            sh[t0] += a0; sh[t1] += a1;
            __syncthreads();
        }
        cur[t0] = sh[t0] - c0;                 // exclusive
        if (t1 < HW) cur[t1] = sh[t1] - c1;
        __syncthreads();
        for (int b = tid; b < HW; b += 256) H[blockIdx.x * HW + b] = cur[b];
        __syncthreads();
        for (int i = tid; i < CHUNK; i += 256) {
            int e = base + i;
            int s = edge_src(ei, e, is64);
            int d = edge_dst(ei, e, is64);
            int pos = base + atomicAdd(&cur[d >> 8], 1);
            ebuf[pos] = ((unsigned int)s << 8) | (unsigned int)(d & 255);
        }
        return;
    }
    // ---- GEMM1 role: rows [bid*64, bid*64+64), fp32 input, bf16 output ----
    int bid = blockIdx.x - BIN_BLOCKS;
    int wave = threadIdx.x >> 6;
    int l = threadIdx.x & 63;
    int kg = l >> 4;
    int row = bid * 64 + wave * 16 + (l & 15);
    int rl = min(row, N_NODES - 1);

    v4f acc[8];
    #pragma unroll
    for (int i = 0; i < 8; ++i)
        for (int r = 0; r < 4; ++r) acc[i][r] = 0.f;

    #pragma unroll
    for (int kt = 0; kt < IN_C / 32; ++kt) {
        v8s a;
        float4 u = *(const float4*)(x + (size_t)rl * IN_C + kt * 32 + kg * 4);
        float4 v = *(const float4*)(x + (size_t)rl * IN_C + kt * 32 + 16 + kg * 4);
        a[0] = f2bf(u.x); a[1] = f2bf(u.y); a[2] = f2bf(u.z); a[3] = f2bf(u.w);
        a[4] = f2bf(v.x); a[5] = f2bf(v.y); a[6] = f2bf(v.z); a[7] = f2bf(v.w);
        const v8s* bp = (const v8s*)W1p + (size_t)(kt * 8) * 64 + l;
        #pragma unroll
        for (int ct = 0; ct < 8; ++ct) {
            v8s b = bp[ct * 64];
            acc[ct] = __builtin_amdgcn_mfma_f32_16x16x32_bf16(a, b, acc[ct], 0, 0, 0);
        }
    }
    int orow0 = bid * 64 + wave * 16 + kg * 4;
    #pragma unroll
    for (int ct = 0; ct < 8; ++ct) {
        #pragma unroll
        for (int r = 0; r < 4; ++r) {
            int orow = orow0 + r;
            if (orow < N_NODES)
                hbf[(size_t)orow * 128 + ct * 16 + (l & 15)] = f2bf(acc[ct][r]);
        }
    }
}

// ---------- per-bucket degree histogram (LDS only, coalesced degi writes) ----------
__global__ __launch_bounds__(256) void bucket_deg(const unsigned int* __restrict__ ebuf,
                                                  const int* __restrict__ H,
                                                  int* __restrict__ degi) {
    __shared__ int segbeg[BIN_BLOCKS], seglen[BIN_BLOCKS];
    __shared__ int hist[256];
    int t = threadIdx.x, b = blockIdx.x;
    int h0 = H[t * HW + b], h1 = H[t * HW + b + 1];
    segbeg[t] = t * CHUNK + h0;
    seglen[t] = h1 - h0;
    hist[t] = 0;
    __syncthreads();
    int wave = t >> 6, lane = t & 63;
    for (int s = wave; s < BIN_BLOCKS; s += 4) {
        int len = seglen[s], beg = segbeg[s];
        for (int j = lane; j < len; j += 64)
            atomicAdd(&hist[ebuf[beg + j] & 255], 1);
    }
    __syncthreads();
    int n = b * 256 + t;
    if (n < N_NODES) degi[n] = hist[t];
}

// ---------- scan phase1 (+ fused dis = rsqrt(1+deg)) ----------
__global__ void scan_phase1(const int* __restrict__ degi, int* __restrict__ rowptr,
                            int* __restrict__ part, float* __restrict__ dis) {
    __shared__ int sh[256];
    int i = blockIdx.x * 256 + threadIdx.x;
    int v = (i < N_NODES) ? degi[i] : 0;
    if (i < N_NODES) dis[i] = rsqrtf(1.0f + (float)v);
    sh[threadIdx.x] = v;
    __syncthreads();
    for (int off = 1; off < 256; off <<= 1) {
        int t = (threadIdx.x >= off) ? sh[threadIdx.x - off] : 0;
        __syncthreads();
        sh[threadIdx.x] += t;
        __syncthreads();
    }
    if (i < N_NODES) rowptr[i] = sh[threadIdx.x] - v;
    if (threadIdx.x == 255) part[blockIdx.x] = sh[255];
}

__global__ void scan_phase2(int* __restrict__ part, int nb) {
    __shared__ int sh[512];
    int tid = threadIdx.x;
    int v = (tid < nb) ? part[tid] : 0;
    sh[tid] = v;
    __syncthreads();
    for (int off = 1; off < 512; off <<= 1) {
        int t = (tid >= off) ? sh[tid - off] : 0;
        __syncthreads();
        sh[tid] += t;
        __syncthreads();
    }
    if (tid < nb) part[tid] = sh[tid] - v;
}

__global__ void scan_phase3(int* __restrict__ rowptr, const int* __restrict__ part) {
    int i = blockIdx.x * 256 + threadIdx.x;
    if (i < N_NODES) rowptr[i] += part[blockIdx.x];
    if (i == N_NODES - 1) rowptr[N_NODES] = E_EDGES;
}

// ---------- per-bucket CSR fill: LDS cursors, bucket-local scattered stores ----------
__global__ __launch_bounds__(256) void csr_fill_bucket(const unsigned int* __restrict__ ebuf,
                                                       const int* __restrict__ H,
                                                       const int* __restrict__ rowptr,
                                                       int* __restrict__ csr_src) {
    __shared__ int segbeg[BIN_BLOCKS], seglen[BIN_BLOCKS];
    __shared__ int cur[256];
    int t = threadIdx.x, b = blockIdx.x;
    int h0 = H[t * HW + b], h1 = H[t * HW + b + 1];
    segbeg[t] = t * CHUNK + h0;
    seglen[t] = h1 - h0;
    int n = b * 256 + t;
    cur[t] = (n < N_NODES) ? rowptr[n] : 0;
    __syncthreads();
    int wave = t >> 6, lane = t & 63;
    for (int s = wave; s < BIN_BLOCKS; s += 4) {
        int len = seglen[s], beg = segbeg[s];
        for (int j = lane; j < len; j += 64) {
            unsigned int v = ebuf[beg + j];
            int pos = atomicAdd(&cur[v & 255], 1);
            csr_src[pos] = (int)(v >> 8);
        }
    }
}

// ---------- GEMM2 with fused BN+ReLU on the A operand ----------
__global__ __launch_bounds__(256) void gemm2_bn_mfma(const float* __restrict__ hpre,
                                                     const float* __restrict__ stats,
                                                     const unsigned short* __restrict__ Wp,
                                                     unsigned short* __restrict__ Cb) {
    int wave = threadIdx.x >> 6;
    int l = threadIdx.x & 63;
    int kg = l >> 4;
    int row = blockIdx.x * 64 + wave * 16 + (l & 15);
    int rl = min(row, N_NODES - 1);

    v4f acc[8];
    #pragma unroll
    for (int i = 0; i < 8; ++i)
        for (int r = 0; r < 4; ++r) acc[i][r] = 0.f;

    #pragma unroll
    for (int kt = 0; kt < HID_C / 32; ++kt) {
        int k0 = kt * 32 + kg * 4;
        float4 u  = *(const float4*)(hpre + (size_t)rl * HID_C + k0);
        float4 v  = *(const float4*)(hpre + (size_t)rl * HID_C + k0 + 16);
        float4 sc0 = *(const float4*)(stats + 256 + k0);
        float4 sh0 = *(const float4*)(stats + 384 + k0);
        float4 sc1 = *(const float4*)(stats + 256 + k0 + 16);
        float4 sh1 = *(const float4*)(stats + 384 + k0 + 16);
        v8s a;
        a[0] = f2bf(fmaxf(u.x * sc0.x + sh0.x, 0.f));
        a[1] = f2bf(fmaxf(u.y * sc0.y + sh0.y, 0.f));
        a[2] = f2bf(fmaxf(u.z * sc0.z + sh0.z, 0.f));
        a[3] = f2bf(fmaxf(u.w * sc0.w + sh0.w, 0.f));
        a[4] = f2bf(fmaxf(v.x * sc1.x + sh1.x, 0.f));
        a[5] = f2bf(fmaxf(v.y * sc1.y + sh1.y, 0.f));
        a[6] = f2bf(fmaxf(v.z * sc1.z + sh1.z, 0.f));
        a[7] = f2bf(fmaxf(v.w * sc1.w + sh1.w, 0.f));
        const v8s* bp = (const v8s*)Wp + (size_t)(kt * 8) * 64 + l;
        #pragma unroll
        for (int ct = 0; ct < 8; ++ct) {
            v8s b = bp[ct * 64];
            acc[ct] = __builtin_amdgcn_mfma_f32_16x16x32_bf16(a, b, acc[ct], 0, 0, 0);
        }
    }
    int orow0 = blockIdx.x * 64 + wave * 16 + kg * 4;
    #pragma unroll
    for (int ct = 0; ct < 8; ++ct) {
        #pragma unroll
        for (int r = 0; r < 4; ++r) {
            int orow = orow0 + r;
            if (orow < N_NODES)
                Cb[(size_t)orow * 128 + ct * 16 + (l & 15)] = f2bf(acc[ct][r]);
        }
    }
}

// ---------- CSR aggregation, unroll-8 independent gathers ----------
template <int SPLIT>
__global__ __launch_bounds__(256) void aggregate_bf16(const unsigned int* __restrict__ hb,
                                                      const int* __restrict__ csr_src,
                                                      const int* __restrict__ rowptr,
                                                      const float* __restrict__ dis,
                                                      const float* __restrict__ bias,
                                                      float* __restrict__ out) {
    int wid = (blockIdx.x * 256 + threadIdx.x) >> 6;
    int lane = threadIdx.x & 63;
    if (wid >= N_NODES) return;
    int beg = rowptr[wid], end = rowptr[wid + 1];
    float dn = dis[wid];
    unsigned int su = hb[(size_t)wid * 64 + lane];
    float2 bv = ((const float2*)bias)[lane];
    float sw = dn * dn;
    float ax = __uint_as_float(su << 16) * sw + bv.x;
    float ay = __uint_as_float(su & 0xffff0000u) * sw + bv.y;
    for (int c = beg; c < end; c += 64) {
        int idx = c + lane;
        int sl = (idx < end) ? csr_src[idx] : 0;
        float wl = (idx < end) ? dis[sl] * dn : 0.0f;
        int cnt = min(64, end - c);
        for (int j = 0; j < cnt; j += 8) {
            int s0 = __shfl(sl, j + 0), s1 = __shfl(sl, j + 1);
            int s2 = __shfl(sl, j + 2), s3 = __shfl(sl, j + 3);
            int s4 = __shfl(sl, j + 4), s5 = __shfl(sl, j + 5);
            int s6 = __shfl(sl, j + 6), s7 = __shfl(sl, j + 7);
            float w0 = __shfl(wl, j + 0), w1 = __shfl(wl, j + 1);
            float w2 = __shfl(wl, j + 2), w3 = __shfl(wl, j + 3);
            float w4 = __shfl(wl, j + 4), w5 = __shfl(wl, j + 5);
            float w6 = __shfl(wl, j + 6), w7 = __shfl(wl, j + 7);
            unsigned int u0 = hb[(size_t)s0 * 64 + lane];
            unsigned int u1 = hb[(size_t)s1 * 64 + lane];
            unsigned int u2 = hb[(size_t)s2 * 64 + lane];
            unsigned int u3 = hb[(size_t)s3 * 64 + lane];
            unsigned int u4 = hb[(size_t)s4 * 64 + lane];
            unsigned int u5 = hb[(size_t)s5 * 64 + lane];
            unsigned int u6 = hb[(size_t)s6 * 64 + lane];
            unsigned int u7 = hb[(size_t)s7 * 64 + lane];
            ax += __uint_as_float(u0 << 16) * w0; ay += __uint_as_float(u0 & 0xffff0000u) * w0;
            ax += __uint_as_float(u1 << 16) * w1; ay += __uint_as_float(u1 & 0xffff0000u) * w1;
            ax += __uint_as_float(u2 << 16) * w2; ay += __uint_as_float(u2 & 0xffff0000u) * w2;
            ax += __uint_as_float(u3 << 16) * w3; ay += __uint_as_float(u3 & 0xffff0000u) * w3;
            ax += __uint_as_float(u4 << 16) * w4; ay += __uint_as_float(u4 & 0xffff0000u) * w4;
            ax += __uint_as_float(u5 << 16) * w5; ay += __uint_as_float(u5 & 0xffff0000u) * w5;
            ax += __uint_as_float(u6 << 16) * w6; ay += __uint_as_float(u6 & 0xffff0000u) * w6;
            ax += __uint_as_float(u7 << 16) * w7; ay += __uint_as_float(u7 & 0xffff0000u) * w7;
        }
    }
    if (SPLIT == 0) {
        float2 o = {ax, ay};
        ((float2*)(out + (size_t)wid * 128))[lane] = o;
    } else {
        int ch = lane * 2;
        size_t off = (ch < 64) ? ((size_t)wid * 64 + ch)
                               : ((size_t)(N_NODES + wid) * 64 + (ch - 64));
        float2 o = {ax, ay};
        *(float2*)(out + off) = o;
    }
}

// ---------- batch norm stats ----------
__global__ void bn_stats(const float* __restrict__ hpre, float* __restrict__ stats) {
    int c = threadIdx.x & 127;
    int half = threadIdx.x >> 7;
    float s = 0.f, s2 = 0.f;
    int rpi = (blockDim.x >> 7) * gridDim.x;
    for (int n = blockIdx.x * 2 + half; n < N_NODES; n += rpi) {
        float v = hpre[(size_t)n * 128 + c];
        s += v; s2 += v * v;
    }
    __shared__ float ls[256], ls2[256];
    ls[threadIdx.x] = s; ls2[threadIdx.x] = s2;
    __syncthreads();
    if (threadIdx.x < 128) {
        s = ls[threadIdx.x] + ls[threadIdx.x + 128];
        s2 = ls2[threadIdx.x] + ls2[threadIdx.x + 128];
        atomicAdd(&stats[c], s);
        atomicAdd(&stats[128 + c], s2);
    }
}

__global__ void bn_finish(float* __restrict__ stats, const float* __restrict__ gamma,
                          const float* __restrict__ beta) {
    int c = threadIdx.x;
    if (c < 128) {
        float mean = stats[c] * (1.0f / N_NODES);
        float var = stats[128 + c] * (1.0f / N_NODES) - mean * mean;
        float scale = rsqrtf(var + BN_EPS) * gamma[c];
        stats[256 + c] = scale;
        stats[384 + c] = beta[c] - mean * scale;
    }
}

extern "C" void kernel_launch(void* const* d_in, const int* in_sizes, int n_in,
                              void* d_out, int out_size, void* d_ws, size_t ws_size,
                              hipStream_t stream) {
    const float* x    = (const float*)d_in[0];
    const int* ei     = (const int*)d_in[1];
    const float* W1   = (const float*)d_in[2];
    const float* b1   = (const float*)d_in[3];
    const float* gamma= (const float*)d_in[4];
    const float* beta = (const float*)d_in[5];
    const float* W2   = (const float*)d_in[6];
    const float* b2   = (const float*)d_in[7];
    const float* W3   = (const float*)d_in[8];
    const float* b3   = (const float*)d_in[9];
    float* out = (float*)d_out;

    char* p = (char*)d_ws;
    auto alloc = [&](size_t bytes) {
        void* r = (void*)p;
        p += (bytes + 511) & ~(size_t)511;
        return r;
    };
    float* dis    = (float*)alloc(N_NODES * 4);
    int*   degi   = (int*)  alloc(N_NODES * 4);
    int*   rowptr = (int*)  alloc((N_NODES + 1) * 4);
    int*   part   = (int*)  alloc(2048);
    float* stats  = (float*)alloc(2048);
    int*   flag   = (int*)  alloc(256);
    float* bcat   = (float*)alloc(512);
    unsigned short* W1p = (unsigned short*)alloc(256 * 128 * 2);
    unsigned short* Wcp = (unsigned short*)alloc(128 * 128 * 2);
    int*   H      = (int*)  alloc((size_t)BIN_BLOCKS * HW * 4);
    unsigned int* ebuf = (unsigned int*)alloc((size_t)E_EDGES * 4);
    int*   csrs   = (int*)  alloc((size_t)E_EDGES * 4);
    unsigned short* hbf  = (unsigned short*)alloc((size_t)N_NODES * 128 * 2);
    float* hpre   = (float*)alloc((size_t)N_NODES * 128 * 4);

    const int NB = (N_NODES + 255) / 256;  // 391
    const int GB = (N_NODES + 63) / 64;    // 1563

    hipMemsetAsync(stats, 0, 1024, stream);

    // dtype detect + weight permutes
    prep_kernel<<<194, 256, 0, stream>>>(ei, flag, W1, W2, W3, b2, b3, W1p, Wcp, bcat);

    // edge binning (counting sort by dst>>8) || GEMM1
    bin_and_gemm1<<<BIN_BLOCKS + GB, 256, 0, stream>>>(ei, flag, ebuf, H, x, W1p, hbf);

    // per-bucket degree histogram -> degi (no global atomics)
    bucket_deg<<<NBUCK, 256, 0, stream>>>(ebuf, H, degi);

    // rowptr scan (+dis)
    scan_phase1<<<NB, 256, 0, stream>>>(degi, rowptr, part, dis);
    scan_phase2<<<1, 512, 0, stream>>>(part, NB);
    scan_phase3<<<NB, 256, 0, stream>>>(rowptr, part);

    // per-bucket CSR fill (LDS cursors)
    csr_fill_bucket<<<NBUCK, 256, 0, stream>>>(ebuf, H, rowptr, csrs);

    // layer 1 aggregate + BN stats
    aggregate_bf16<0><<<(N_NODES * 64 + 255) / 256, 256, 0, stream>>>(
        (const unsigned int*)hbf, csrs, rowptr, dis, b1, hpre);
    bn_stats<<<512, 256, 0, stream>>>(hpre, stats);
    bn_finish<<<1, 128, 0, stream>>>(stats, gamma, beta);

    // layer 2: BN+ReLU fused into GEMM2's A-load
    gemm2_bn_mfma<<<GB, 256, 0, stream>>>(hpre, stats, Wcp, hbf);
    aggregate_bf16<1><<<(N_NODES * 64 + 255) / 256, 256, 0, stream>>>(
        (const unsigned int*)hbf, csrs, rowptr, dis, bcat, out);
}

// Round 7
// 258.630 us; speedup vs baseline: 11.7524x; 1.1674x over previous
//
#include <hip/hip_runtime.h>

#define N_NODES 100000
#define E_EDGES 1600000
#define IN_C 256
#define HID_C 128
#define BN_EPS 1e-5f

#define NBUCK 391                      // buckets of 256 nodes: dst >> 8
#define BIN_BLOCKS 256
#define CHUNK (E_EDGES / BIN_BLOCKS)   // 6250
#define HW 392                         // segment-table row width (incl. sentinel)
#define AGG_BLOCKS 1024                // aggregate_bn grid

using v8s = __attribute__((ext_vector_type(8))) short;
using v4f = __attribute__((ext_vector_type(4))) float;

__device__ __forceinline__ unsigned short f2bf(float f) {
    unsigned int u = __float_as_uint(f);
    u += 0x7fffu + ((u >> 16) & 1u);
    return (unsigned short)(u >> 16);
}

// ---------- edge index accessors (int32 vs int64 detected at runtime) ----------
__device__ __forceinline__ int edge_src(const int* ei, int e, int is64) {
    return is64 ? ei[2 * e] : ei[e];
}
__device__ __forceinline__ int edge_dst(const int* ei, int e, int is64) {
    return is64 ? ei[2 * E_EDGES + 2 * e] : ei[E_EDGES + e];
}

// ---------- prep: dtype detect (block 0) + weight permutes (blocks 1..193) ----------
__global__ void prep_kernel(const int* __restrict__ ei, int* __restrict__ flag,
                            const float* __restrict__ W1, const float* __restrict__ W2,
                            const float* __restrict__ W3, const float* __restrict__ b2,
                            const float* __restrict__ b3,
                            unsigned short* __restrict__ W1p,
                            unsigned short* __restrict__ Wcp,
                            float* __restrict__ bcat) {
    __shared__ int any;
    if (blockIdx.x == 0) {
        if (threadIdx.x == 0) any = 0;
        __syncthreads();
        int v = 0;
        for (int i = threadIdx.x; i < 4096; i += blockDim.x) v |= ei[2 * i + 1];
        if (v) atomicOr(&any, 1);
        __syncthreads();
        if (threadIdx.x == 0) *flag = any ? 0 : 1;
        return;
    }
    int t = (blockIdx.x - 1) * 256 + threadIdx.x;
    if (t < 32768) {                       // W1p: K=256
        int j = t & 7, l = (t >> 3) & 63, ct = (t >> 9) & 7, kt = t >> 12;
        int k = kt * 32 + ((l >> 4) << 2) + (j & 3) + ((j >> 2) << 4);
        int n = ct * 16 + (l & 15);
        W1p[t] = f2bf(W1[k * 128 + n]);
    } else if (t < 49152) {                // Wcp: K=128, cols = [W2|W3]
        int u = t - 32768;
        int j = u & 7, l = (u >> 3) & 63, ct = (u >> 9) & 7, kt = u >> 12;
        int k = kt * 32 + ((l >> 4) << 2) + (j & 3) + ((j >> 2) << 4);
        int n = ct * 16 + (l & 15);
        float v = (n < 64) ? W2[k * 64 + n] : W3[k * 64 + (n - 64)];
        Wcp[u] = f2bf(v);
    } else if (t < 49280) {
        int c = t - 49152;
        bcat[c] = (c < 64) ? b2[c] : b3[c - 64];
    }
}

// ---------- fused: per-block counting sort of edges by dst-bucket || GEMM1 ----------
__global__ __launch_bounds__(256, 2) void bin_and_gemm1(
    const int* __restrict__ ei, const int* __restrict__ flag,
    unsigned int* __restrict__ ebuf, int* __restrict__ H,
    const float* __restrict__ x, const unsigned short* __restrict__ W1p,
    unsigned short* __restrict__ hbf) {
    __shared__ int sh[512];
    __shared__ int cur[HW];
    if (blockIdx.x < BIN_BLOCKS) {
        int tid = threadIdx.x;
        int is64 = *flag;
        int base = blockIdx.x * CHUNK;
        sh[tid] = 0; sh[tid + 256] = 0;
        __syncthreads();
        for (int i = tid; i < CHUNK; i += 256) {
            int d = edge_dst(ei, base + i, is64);
            atomicAdd(&sh[d >> 8], 1);
        }
        __syncthreads();
        int t0 = tid, t1 = tid + 256;
        int c0 = sh[t0], c1 = sh[t1];
        for (int off = 1; off < 512; off <<= 1) {
            int a0 = (t0 >= off) ? sh[t0 - off] : 0;
            int a1 = (t1 >= off) ? sh[t1 - off] : 0;
            __syncthreads();
            sh[t0] += a0; sh[t1] += a1;
            __syncthreads();
        }
        cur[t0] = sh[t0] - c0;                 // exclusive
        if (t1 < HW) cur[t1] = sh[t1] - c1;
        __syncthreads();
        for (int b = tid; b < HW; b += 256) H[blockIdx.x * HW + b] = cur[b];
        __syncthreads();
        for (int i = tid; i < CHUNK; i += 256) {
            int e = base + i;
            int s = edge_src(ei, e, is64);
            int d = edge_dst(ei, e, is64);
            int pos = base + atomicAdd(&cur[d >> 8], 1);
            ebuf[pos] = ((unsigned int)s << 8) | (unsigned int)(d & 255);
        }
        return;
    }
    // ---- GEMM1 role: software-pipelined, rows [bid*64, +64), fp32 in, bf16 out ----
    int bid = blockIdx.x - BIN_BLOCKS;
    int wave = threadIdx.x >> 6;
    int l = threadIdx.x & 63;
    int kg = l >> 4;
    int row = bid * 64 + wave * 16 + (l & 15);
    int rl = min(row, N_NODES - 1);
    const float* xr = x + (size_t)rl * IN_C + kg * 4;

    v4f acc[8];
    #pragma unroll
    for (int i = 0; i < 8; ++i)
        for (int r = 0; r < 4; ++r) acc[i][r] = 0.f;

    float4 u = *(const float4*)(xr);
    float4 v = *(const float4*)(xr + 16);
    #pragma unroll
    for (int kt = 0; kt < IN_C / 32; ++kt) {
        // issue all 8 B-frag loads (independent, in flight together)
        v8s bfr[8];
        const v8s* bp = (const v8s*)W1p + (size_t)(kt * 8) * 64 + l;
        #pragma unroll
        for (int ct = 0; ct < 8; ++ct) bfr[ct] = bp[ct * 64];
        // convert current A
        v8s a;
        a[0] = f2bf(u.x); a[1] = f2bf(u.y); a[2] = f2bf(u.z); a[3] = f2bf(u.w);
        a[4] = f2bf(v.x); a[5] = f2bf(v.y); a[6] = f2bf(v.z); a[7] = f2bf(v.w);
        // prefetch next A under the MFMA chain
        if (kt < IN_C / 32 - 1) {
            u = *(const float4*)(xr + (kt + 1) * 32);
            v = *(const float4*)(xr + (kt + 1) * 32 + 16);
        }
        #pragma unroll
        for (int ct = 0; ct < 8; ++ct)
            acc[ct] = __builtin_amdgcn_mfma_f32_16x16x32_bf16(a, bfr[ct], acc[ct], 0, 0, 0);
    }
    int orow0 = bid * 64 + wave * 16 + kg * 4;
    #pragma unroll
    for (int ct = 0; ct < 8; ++ct) {
        #pragma unroll
        for (int r = 0; r < 4; ++r) {
            int orow = orow0 + r;
            if (orow < N_NODES)
                hbf[(size_t)orow * 128 + ct * 16 + (l & 15)] = f2bf(acc[ct][r]);
        }
    }
}

// ---------- fused: per-bucket degree histogram + local scan -> rowptr/part/dis ----------
__global__ __launch_bounds__(256) void bucket_scan1(const unsigned int* __restrict__ ebuf,
                                                    const int* __restrict__ H,
                                                    int* __restrict__ rowptr,
                                                    int* __restrict__ part,
                                                    float* __restrict__ dis) {
    __shared__ int segbeg[BIN_BLOCKS], seglen[BIN_BLOCKS];
    __shared__ int hist[256];
    __shared__ int sc[256];
    int t = threadIdx.x, b = blockIdx.x;
    int h0 = H[t * HW + b], h1 = H[t * HW + b + 1];
    segbeg[t] = t * CHUNK + h0;
    seglen[t] = h1 - h0;
    hist[t] = 0;
    __syncthreads();
    int wv = t >> 6, lane = t & 63;
    int sg = lane >> 4, sl = lane & 15;           // 16 concurrent segments
    for (int s = wv * 4 + sg; s < BIN_BLOCKS; s += 16) {
        int len = seglen[s], beg = segbeg[s];
        for (int j = sl; j < len; j += 16)
            atomicAdd(&hist[ebuf[beg + j] & 255], 1);
    }
    __syncthreads();
    int deg = hist[t];
    int n = b * 256 + t;
    if (n < N_NODES) dis[n] = rsqrtf(1.0f + (float)deg);
    sc[t] = deg;
    __syncthreads();
    for (int off = 1; off < 256; off <<= 1) {
        int a = (t >= off) ? sc[t - off] : 0;
        __syncthreads();
        sc[t] += a;
        __syncthreads();
    }
    if (n < N_NODES) rowptr[n] = sc[t] - deg;     // exclusive, bucket-local
    if (t == 255) part[b] = sc[255];
}

__global__ void scan_phase2(int* __restrict__ part, int nb) {
    __shared__ int sh[512];
    int tid = threadIdx.x;
    int v = (tid < nb) ? part[tid] : 0;
    sh[tid] = v;
    __syncthreads();
    for (int off = 1; off < 512; off <<= 1) {
        int t = (tid >= off) ? sh[tid - off] : 0;
        __syncthreads();
        sh[tid] += t;
        __syncthreads();
    }
    if (tid < nb) part[tid] = sh[tid] - v;
}

__global__ void scan_phase3(int* __restrict__ rowptr, const int* __restrict__ part) {
    int i = blockIdx.x * 256 + threadIdx.x;
    if (i < N_NODES) rowptr[i] += part[blockIdx.x];
    if (i == N_NODES - 1) rowptr[N_NODES] = E_EDGES;
}

// ---------- per-bucket CSR fill: LDS cursors, 16-lane sub-segments ----------
__global__ __launch_bounds__(256) void csr_fill_bucket(const unsigned int* __restrict__ ebuf,
                                                       const int* __restrict__ H,
                                                       const int* __restrict__ rowptr,
                                                       int* __restrict__ csr_src) {
    __shared__ int segbeg[BIN_BLOCKS], seglen[BIN_BLOCKS];
    __shared__ int cur[256];
    int t = threadIdx.x, b = blockIdx.x;
    int h0 = H[t * HW + b], h1 = H[t * HW + b + 1];
    segbeg[t] = t * CHUNK + h0;
    seglen[t] = h1 - h0;
    int n = b * 256 + t;
    cur[t] = (n < N_NODES) ? rowptr[n] : 0;
    __syncthreads();
    int wv = t >> 6, lane = t & 63;
    int sg = lane >> 4, sl = lane & 15;
    for (int s = wv * 4 + sg; s < BIN_BLOCKS; s += 16) {
        int len = seglen[s], beg = segbeg[s];
        for (int j = sl; j < len; j += 16) {
            unsigned int v = ebuf[beg + j];
            int pos = atomicAdd(&cur[v & 255], 1);
            csr_src[pos] = (int)(v >> 8);
        }
    }
}

// ---------- aggregate layer1 + fused BN partial stats; emits bf16 table ----------
__global__ __launch_bounds__(256) void aggregate_bn(const unsigned int* __restrict__ hb,
                                                    const int* __restrict__ csr_src,
                                                    const int* __restrict__ rowptr,
                                                    const float* __restrict__ dis,
                                                    const float* __restrict__ bias,
                                                    unsigned int* __restrict__ h2bf,
                                                    float* __restrict__ partials) {
    int lane = threadIdx.x & 63;
    int wv = threadIdx.x >> 6;
    float2 bv = ((const float2*)bias)[lane];
    float s0 = 0.f, s1 = 0.f, q0 = 0.f, q1 = 0.f;
    for (int wid = blockIdx.x * 4 + wv; wid < N_NODES; wid += AGG_BLOCKS * 4) {
        int beg = rowptr[wid], end = rowptr[wid + 1];
        float dn = dis[wid];
        unsigned int su = hb[(size_t)wid * 64 + lane];
        float sw = dn * dn;
        float ax = __uint_as_float(su << 16) * sw + bv.x;
        float ay = __uint_as_float(su & 0xffff0000u) * sw + bv.y;
        for (int c = beg; c < end; c += 64) {
            int idx = c + lane;
            int sl = (idx < end) ? csr_src[idx] : 0;
            float wl = (idx < end) ? dis[sl] * dn : 0.0f;
            int cnt = min(64, end - c);
            for (int j = 0; j < cnt; j += 8) {
                int e0 = __shfl(sl, j + 0), e1 = __shfl(sl, j + 1);
                int e2 = __shfl(sl, j + 2), e3 = __shfl(sl, j + 3);
                int e4 = __shfl(sl, j + 4), e5 = __shfl(sl, j + 5);
                int e6 = __shfl(sl, j + 6), e7 = __shfl(sl, j + 7);
                float w0 = __shfl(wl, j + 0), w1 = __shfl(wl, j + 1);
                float w2 = __shfl(wl, j + 2), w3 = __shfl(wl, j + 3);
                float w4 = __shfl(wl, j + 4), w5 = __shfl(wl, j + 5);
                float w6 = __shfl(wl, j + 6), w7 = __shfl(wl, j + 7);
                unsigned int u0 = hb[(size_t)e0 * 64 + lane];
                unsigned int u1 = hb[(size_t)e1 * 64 + lane];
                unsigned int u2 = hb[(size_t)e2 * 64 + lane];
                unsigned int u3 = hb[(size_t)e3 * 64 + lane];
                unsigned int u4 = hb[(size_t)e4 * 64 + lane];
                unsigned int u5 = hb[(size_t)e5 * 64 + lane];
                unsigned int u6 = hb[(size_t)e6 * 64 + lane];
                unsigned int u7 = hb[(size_t)e7 * 64 + lane];
                ax += __uint_as_float(u0 << 16) * w0; ay += __uint_as_float(u0 & 0xffff0000u) * w0;
                ax += __uint_as_float(u1 << 16) * w1; ay += __uint_as_float(u1 & 0xffff0000u) * w1;
                ax += __uint_as_float(u2 << 16) * w2; ay += __uint_as_float(u2 & 0xffff0000u) * w2;
                ax += __uint_as_float(u3 << 16) * w3; ay += __uint_as_float(u3 & 0xffff0000u) * w3;
                ax += __uint_as_float(u4 << 16) * w4; ay += __uint_as_float(u4 & 0xffff0000u) * w4;
                ax += __uint_as_float(u5 << 16) * w5; ay += __uint_as_float(u5 & 0xffff0000u) * w5;
                ax += __uint_as_float(u6 << 16) * w6; ay += __uint_as_float(u6 & 0xffff0000u) * w6;
                ax += __uint_as_float(u7 << 16) * w7; ay += __uint_as_float(u7 & 0xffff0000u) * w7;
            }
        }
        h2bf[(size_t)wid * 64 + lane] = ((unsigned int)f2bf(ay) << 16) | f2bf(ax);
        s0 += ax; q0 += ax * ax;
        s1 += ay; q1 += ay * ay;
    }
    // cross-wave reduce: channel c = 2*lane (+1); 128 channels
    __shared__ float red[4][128];
    red[wv][2 * lane] = s0; red[wv][2 * lane + 1] = s1;
    __syncthreads();
    if (threadIdx.x < 128)
        partials[blockIdx.x * 256 + threadIdx.x] =
            red[0][threadIdx.x] + red[1][threadIdx.x] + red[2][threadIdx.x] + red[3][threadIdx.x];
    __syncthreads();
    red[wv][2 * lane] = q0; red[wv][2 * lane + 1] = q1;
    __syncthreads();
    if (threadIdx.x < 128)
        partials[blockIdx.x * 256 + 128 + threadIdx.x] =
            red[0][threadIdx.x] + red[1][threadIdx.x] + red[2][threadIdx.x] + red[3][threadIdx.x];
}

// ---------- reduce BN partials -> scale/shift ----------
__global__ void bn_reduce(const float* __restrict__ partials,
                          const float* __restrict__ gamma, const float* __restrict__ beta,
                          float* __restrict__ bnab) {
    __shared__ float acc[256];
    int t = threadIdx.x;
    float s = 0.f;
    for (int b = 0; b < AGG_BLOCKS; ++b) s += partials[b * 256 + t];
    acc[t] = s;
    __syncthreads();
    if (t < 128) {
        float mean = acc[t] * (1.0f / N_NODES);
        float var = acc[128 + t] * (1.0f / N_NODES) - mean * mean;
        float scale = rsqrtf(var + BN_EPS) * gamma[t];
        bnab[t] = scale;
        bnab[128 + t] = beta[t] - mean * scale;
    }
}

// ---------- GEMM2: bf16 table in, BN+ReLU fused on A, software-pipelined ----------
__global__ __launch_bounds__(256, 2) void gemm2_bn_mfma(const unsigned short* __restrict__ h2,
                                                        const float* __restrict__ bnab,
                                                        const unsigned short* __restrict__ Wp,
                                                        unsigned short* __restrict__ Cb) {
    __shared__ float ss[256];
    ss[threadIdx.x] = bnab[threadIdx.x];
    __syncthreads();
    int wave = threadIdx.x >> 6;
    int l = threadIdx.x & 63;
    int kg = l >> 4;
    int row = blockIdx.x * 64 + wave * 16 + (l & 15);
    int rl = min(row, N_NODES - 1);
    const unsigned short* ar = h2 + (size_t)rl * HID_C + kg * 4;

    v4f acc[8];
    #pragma unroll
    for (int i = 0; i < 8; ++i)
        for (int r = 0; r < 4; ++r) acc[i][r] = 0.f;

    uint2 p0 = *(const uint2*)(ar);
    uint2 p1 = *(const uint2*)(ar + 16);
    #pragma unroll
    for (int kt = 0; kt < HID_C / 32; ++kt) {
        v8s bfr[8];
        const v8s* bp = (const v8s*)Wp + (size_t)(kt * 8) * 64 + l;
        #pragma unroll
        for (int ct = 0; ct < 8; ++ct) bfr[ct] = bp[ct * 64];
        int k0 = kt * 32 + kg * 4;
        v8s a;
        {
            float v0 = __uint_as_float(p0.x << 16),        v1 = __uint_as_float(p0.x & 0xffff0000u);
            float v2 = __uint_as_float(p0.y << 16),        v3 = __uint_as_float(p0.y & 0xffff0000u);
            float v4 = __uint_as_float(p1.x << 16),        v5 = __uint_as_float(p1.x & 0xffff0000u);
            float v6 = __uint_as_float(p1.y << 16),        v7 = __uint_as_float(p1.y & 0xffff0000u);
            a[0] = f2bf(fmaxf(v0 * ss[k0 + 0] + ss[128 + k0 + 0], 0.f));
            a[1] = f2bf(fmaxf(v1 * ss[k0 + 1] + ss[128 + k0 + 1], 0.f));
            a[2] = f2bf(fmaxf(v2 * ss[k0 + 2] + ss[128 + k0 + 2], 0.f));
            a[3] = f2bf(fmaxf(v3 * ss[k0 + 3] + ss[128 + k0 + 3], 0.f));
            a[4] = f2bf(fmaxf(v4 * ss[k0 + 16] + ss[128 + k0 + 16], 0.f));
            a[5] = f2bf(fmaxf(v5 * ss[k0 + 17] + ss[128 + k0 + 17], 0.f));
            a[6] = f2bf(fmaxf(v6 * ss[k0 + 18] + ss[128 + k0 + 18], 0.f));
            a[7] = f2bf(fmaxf(v7 * ss[k0 + 19] + ss[128 + k0 + 19], 0.f));
        }
        if (kt < HID_C / 32 - 1) {
            p0 = *(const uint2*)(ar + (kt + 1) * 32);
            p1 = *(const uint2*)(ar + (kt + 1) * 32 + 16);
        }
        #pragma unroll
        for (int ct = 0; ct < 8; ++ct)
            acc[ct] = __builtin_amdgcn_mfma_f32_16x16x32_bf16(a, bfr[ct], acc[ct], 0, 0, 0);
    }
    int orow0 = blockIdx.x * 64 + wave * 16 + kg * 4;
    #pragma unroll
    for (int ct = 0; ct < 8; ++ct) {
        #pragma unroll
        for (int r = 0; r < 4; ++r) {
            int orow = orow0 + r;
            if (orow < N_NODES)
                Cb[(size_t)orow * 128 + ct * 16 + (l & 15)] = f2bf(acc[ct][r]);
        }
    }
}

// ---------- layer-2 aggregation into split output ----------
__global__ __launch_bounds__(256) void aggregate_out(const unsigned int* __restrict__ hb,
                                                     const int* __restrict__ csr_src,
                                                     const int* __restrict__ rowptr,
                                                     const float* __restrict__ dis,
                                                     const float* __restrict__ bias,
                                                     float* __restrict__ out) {
    int wid = (blockIdx.x * 256 + threadIdx.x) >> 6;
    int lane = threadIdx.x & 63;
    if (wid >= N_NODES) return;
    int beg = rowptr[wid], end = rowptr[wid + 1];
    float dn = dis[wid];
    unsigned int su = hb[(size_t)wid * 64 + lane];
    float2 bv = ((const float2*)bias)[lane];
    float sw = dn * dn;
    float ax = __uint_as_float(su << 16) * sw + bv.x;
    float ay = __uint_as_float(su & 0xffff0000u) * sw + bv.y;
    for (int c = beg; c < end; c += 64) {
        int idx = c + lane;
        int sl = (idx < end) ? csr_src[idx] : 0;
        float wl = (idx < end) ? dis[sl] * dn : 0.0f;
        int cnt = min(64, end - c);
        for (int j = 0; j < cnt; j += 8) {
            int e0 = __shfl(sl, j + 0), e1 = __shfl(sl, j + 1);
            int e2 = __shfl(sl, j + 2), e3 = __shfl(sl, j + 3);
            int e4 = __shfl(sl, j + 4), e5 = __shfl(sl, j + 5);
            int e6 = __shfl(sl, j + 6), e7 = __shfl(sl, j + 7);
            float w0 = __shfl(wl, j + 0), w1 = __shfl(wl, j + 1);
            float w2 = __shfl(wl, j + 2), w3 = __shfl(wl, j + 3);
            float w4 = __shfl(wl, j + 4), w5 = __shfl(wl, j + 5);
            float w6 = __shfl(wl, j + 6), w7 = __shfl(wl, j + 7);
            unsigned int u0 = hb[(size_t)e0 * 64 + lane];
            unsigned int u1 = hb[(size_t)e1 * 64 + lane];
            unsigned int u2 = hb[(size_t)e2 * 64 + lane];
            unsigned int u3 = hb[(size_t)e3 * 64 + lane];
            unsigned int u4 = hb[(size_t)e4 * 64 + lane];
            unsigned int u5 = hb[(size_t)e5 * 64 + lane];
            unsigned int u6 = hb[(size_t)e6 * 64 + lane];
            unsigned int u7 = hb[(size_t)e7 * 64 + lane];
            ax += __uint_as_float(u0 << 16) * w0; ay += __uint_as_float(u0 & 0xffff0000u) * w0;
            ax += __uint_as_float(u1 << 16) * w1; ay += __uint_as_float(u1 & 0xffff0000u) * w1;
            ax += __uint_as_float(u2 << 16) * w2; ay += __uint_as_float(u2 & 0xffff0000u) * w2;
            ax += __uint_as_float(u3 << 16) * w3; ay += __uint_as_float(u3 & 0xffff0000u) * w3;
            ax += __uint_as_float(u4 << 16) * w4; ay += __uint_as_float(u4 & 0xffff0000u) * w4;
            ax += __uint_as_float(u5 << 16) * w5; ay += __uint_as_float(u5 & 0xffff0000u) * w5;
            ax += __uint_as_float(u6 << 16) * w6; ay += __uint_as_float(u6 & 0xffff0000u) * w6;
            ax += __uint_as_float(u7 << 16) * w7; ay += __uint_as_float(u7 & 0xffff0000u) * w7;
        }
    }
    int ch = lane * 2;
    size_t off = (ch < 64) ? ((size_t)wid * 64 + ch)
                           : ((size_t)(N_NODES + wid) * 64 + (ch - 64));
    float2 o = {ax, ay};
    *(float2*)(out + off) = o;
}

extern "C" void kernel_launch(void* const* d_in, const int* in_sizes, int n_in,
                              void* d_out, int out_size, void* d_ws, size_t ws_size,
                              hipStream_t stream) {
    const float* x    = (const float*)d_in[0];
    const int* ei     = (const int*)d_in[1];
    const float* W1   = (const float*)d_in[2];
    const float* b1   = (const float*)d_in[3];
    const float* gamma= (const float*)d_in[4];
    const float* beta = (const float*)d_in[5];
    const float* W2   = (const float*)d_in[6];
    const float* b2   = (const float*)d_in[7];
    const float* W3   = (const float*)d_in[8];
    const float* b3   = (const float*)d_in[9];
    float* out = (float*)d_out;

    char* p = (char*)d_ws;
    auto alloc = [&](size_t bytes) {
        void* r = (void*)p;
        p += (bytes + 511) & ~(size_t)511;
        return r;
    };
    float* dis    = (float*)alloc(N_NODES * 4);
    int*   rowptr = (int*)  alloc((N_NODES + 1) * 4);
    int*   part   = (int*)  alloc(2048);
    float* bnab   = (float*)alloc(1024);
    int*   flag   = (int*)  alloc(256);
    float* bcat   = (float*)alloc(512);
    unsigned short* W1p = (unsigned short*)alloc(256 * 128 * 2);
    unsigned short* Wcp = (unsigned short*)alloc(128 * 128 * 2);
    int*   H      = (int*)  alloc((size_t)BIN_BLOCKS * HW * 4);
    unsigned int* ebuf = (unsigned int*)alloc((size_t)E_EDGES * 4);
    int*   csrs   = (int*)  alloc((size_t)E_EDGES * 4);
    unsigned int* hbf  = (unsigned int*)alloc((size_t)N_NODES * 64 * 4);   // gemm1 out / gemm2 out
    unsigned int* h2bf = (unsigned int*)alloc((size_t)N_NODES * 64 * 4);   // agg1 bf16 out
    float* partials = (float*)alloc((size_t)AGG_BLOCKS * 256 * 4);

    const int NB = (N_NODES + 255) / 256;  // 391
    const int GB = (N_NODES + 63) / 64;    // 1563

    // dtype detect + weight permutes
    prep_kernel<<<194, 256, 0, stream>>>(ei, flag, W1, W2, W3, b2, b3, W1p, Wcp, bcat);

    // edge binning || GEMM1
    bin_and_gemm1<<<BIN_BLOCKS + GB, 256, 0, stream>>>(ei, flag, ebuf, H, x, W1p,
                                                       (unsigned short*)hbf);

    // per-bucket degree + local scan (+dis)
    bucket_scan1<<<NBUCK, 256, 0, stream>>>(ebuf, H, rowptr, part, dis);
    scan_phase2<<<1, 512, 0, stream>>>(part, NBUCK);
    scan_phase3<<<NB, 256, 0, stream>>>(rowptr, part);

    // per-bucket CSR fill
    csr_fill_bucket<<<NBUCK, 256, 0, stream>>>(ebuf, H, rowptr, csrs);

    // layer 1 aggregate + fused BN partials; emits bf16
    aggregate_bn<<<AGG_BLOCKS, 256, 0, stream>>>(hbf, csrs, rowptr, dis, b1, h2bf, partials);
    bn_reduce<<<1, 256, 0, stream>>>(partials, gamma, beta, bnab);

    // layer 2: BN+ReLU fused into GEMM2's A-path; out bf16 into hbf (dead)
    gemm2_bn_mfma<<<GB, 256, 0, stream>>>((const unsigned short*)h2bf, bnab, Wcp,
                                          (unsigned short*)hbf);
    aggregate_out<<<(N_NODES * 64 + 255) / 256, 256, 0, stream>>>(
        hbf, csrs, rowptr, dis, bcat, out);
}